// Round 9
// baseline (155.375 us; speedup 1.0000x reference)
//
#include <hip/hip_runtime.h>
#include <hip/hip_bf16.h>

#define HW    1600
#define NB    2
#define NHEAD 8
#define HD    32
#define WS2   225
#define WDIM  40
#define CDIM  256
#define PROJ  819200                 // NB*NHEAD*HW*HD elements
#define RELSTR 248                   // LDS rel row stride (multiple of 8 shorts = 16B)
#define TSC   5.656854249492381f     // sqrt(32)

typedef __attribute__((ext_vector_type(8))) short short8;
typedef __attribute__((ext_vector_type(4))) short short4v;
typedef __attribute__((ext_vector_type(4))) float floatx4;

static __device__ __forceinline__ float bu2f(short u) {
    return __uint_as_float(((unsigned)(unsigned short)u) << 16);
}
static __device__ __forceinline__ short f2bu(float f) {
    __hip_bfloat16 h = __float2bfloat16(f);
    short s; __builtin_memcpy(&s, &h, 2); return s;
}
static __device__ __forceinline__ unsigned pk2(short a, short b) {
    return (unsigned)(unsigned short)a | ((unsigned)(unsigned short)b << 16);
}
static __device__ __forceinline__ float ldf(const void* p, size_t i, bool f32) {
    return f32 ? ((const float*)p)[i] : __bfloat162float(((const __hip_bfloat16*)p)[i]);
}
static __device__ __forceinline__ void st_out(void* p, size_t i, float v, bool f32) {
    if (f32) ((float*)p)[i] = v;
    else     ((__hip_bfloat16*)p)[i] = __float2bfloat16(v);
}

// ---------------- Kernel 1: prep = dtype detect + all weight conversions ----------
__global__ __launch_bounds__(256) void prep_kernel(
    const void* __restrict__ q, const void* __restrict__ relv,
    const void* __restrict__ Wq, const void* __restrict__ Wk,
    const void* __restrict__ Wv, const void* __restrict__ Wp,
    const void* __restrict__ bq, const void* __restrict__ bk,
    const void* __restrict__ bv, const void* __restrict__ bp,
    const void* __restrict__ rkw, const void* __restrict__ rkb,
    int* __restrict__ flag, __hip_bfloat16* __restrict__ relvT,
    __hip_bfloat16* __restrict__ Wqb, __hip_bfloat16* __restrict__ Wkb,
    __hip_bfloat16* __restrict__ Wvb, __hip_bfloat16* __restrict__ Wpb,
    float* __restrict__ bqf, float* __restrict__ bkf,
    float* __restrict__ bvf, float* __restrict__ bpf,
    __hip_bfloat16* __restrict__ rkwb, __hip_bfloat16* __restrict__ rkbb)
{
    __shared__ int sbad;
    if (threadIdx.x == 0) sbad = 0;
    __syncthreads();
    int bad = 0;
    const __hip_bfloat16* qb = (const __hip_bfloat16*)q;
    for (int i = threadIdx.x; i < 4096; i += 256) {
        float v = __bfloat162float(qb[i]);
        if (!(v > -1e6f && v < 1e6f)) bad = 1;   // fp32-misread garbage / NaN
    }
    if (bad) sbad = 1;
    __syncthreads();
    const bool f32 = (sbad != 0);
    if (blockIdx.x == 0 && threadIdx.x == 0) *flag = sbad;

    const int gid = blockIdx.x * 256 + threadIdx.x;
    const int gsz = gridDim.x * 256;

    // relvT: [h][w][d] transpose of relv [h][d][w]
    for (int e = gid; e < NHEAD * WS2 * HD; e += gsz) {
        const int h = e / (WS2 * HD), idx = e - h * (WS2 * HD);
        const int w = idx >> 5, d = idx & 31;
        relvT[e] = __float2bfloat16(ldf(relv, ((size_t)h * HD + d) * WS2 + w, f32));
    }
    for (int e = gid; e < CDIM * CDIM; e += gsz) {
        Wqb[e] = __float2bfloat16(ldf(Wq, e, f32));
        Wkb[e] = __float2bfloat16(ldf(Wk, e, f32));
        Wvb[e] = __float2bfloat16(ldf(Wv, e, f32));
        Wpb[e] = __float2bfloat16(ldf(Wp, e, f32));
    }
    for (int e = gid; e < CDIM; e += gsz) {
        bqf[e] = ldf(bq, e, f32); bkf[e] = ldf(bk, e, f32);
        bvf[e] = ldf(bv, e, f32); bpf[e] = ldf(bp, e, f32);
    }
    for (int e = gid; e < NHEAD * WS2 * HD; e += gsz)
        rkwb[e] = __float2bfloat16(ldf(rkw, e, f32));
    for (int e = gid; e < NHEAD * WS2; e += gsz)
        rkbb[e] = __float2bfloat16(ldf(rkb, e, f32));
}

// ---------------- Kernel 2: fused transpose + projection GEMM (q,k,v) -------------
// 512 threads / 8 waves per block: staging split across thread-halves,
// each wave computes 2 o-tile-groups.
__global__ __launch_bounds__(512) void proj_fused(
    const void* __restrict__ xq, const void* __restrict__ xk, const void* __restrict__ xv,
    const __hip_bfloat16* __restrict__ Wqb, const float* __restrict__ bqf,
    const __hip_bfloat16* __restrict__ Wkb, const float* __restrict__ bkf,
    const __hip_bfloat16* __restrict__ Wvb, const float* __restrict__ bvf,
    const int* __restrict__ flag,
    __hip_bfloat16* __restrict__ qs, __hip_bfloat16* __restrict__ ks,
    __hip_bfloat16* __restrict__ vs)
{
    __shared__ short xt[32][264];
    const bool f32 = (*flag != 0);
    const int tid = threadIdx.x;
    const int m0 = blockIdx.x * 32;
    const int n  = blockIdx.y;
    const int t  = blockIdx.z;
    const void* x; const short* W; const float* bias; __hip_bfloat16* dst; float scale;
    if (t == 0)      { x = xq; W = (const short*)Wqb; bias = bqf; dst = qs; scale = 0.17677669529663687f; }
    else if (t == 1) { x = xk; W = (const short*)Wkb; bias = bkf; dst = ks; scale = 1.f; }
    else             { x = xv; W = (const short*)Wvb; bias = bvf; dst = vs; scale = 1.f; }

    {
        const int c  = tid & 255;
        const int gh = tid >> 8;                    // which 16-row half of the tile
        const size_t xb = ((size_t)n * CDIM + c) * HW + m0 + gh * 16;
        if (f32) {
            const float* xr = (const float*)x + xb;
            #pragma unroll
            for (int g = 0; g < 4; ++g) {
                float4 f = *(const float4*)(xr + g * 4);
                xt[gh*16 + g*4+0][c] = f2bu(f.x); xt[gh*16 + g*4+1][c] = f2bu(f.y);
                xt[gh*16 + g*4+2][c] = f2bu(f.z); xt[gh*16 + g*4+3][c] = f2bu(f.w);
            }
        } else {
            const __hip_bfloat16* xr = (const __hip_bfloat16*)x + xb;
            short8 s0 = *(const short8*)(xr);
            short8 s1 = *(const short8*)(xr + 8);
            #pragma unroll
            for (int u = 0; u < 8; ++u) {
                xt[gh*16 + u][c]     = s0[u];
                xt[gh*16 + 8 + u][c] = s1[u];
            }
        }
    }
    __syncthreads();

    const int wave = tid >> 6, lane = tid & 63;     // wave 0..7
    const int m = lane & 15, qd = lane >> 4;

    short8 A[2][8];
    #pragma unroll
    for (int mt = 0; mt < 2; ++mt)
        #pragma unroll
        for (int k = 0; k < 8; ++k)
            A[mt][k] = *(const short8*)(&xt[mt*16 + m][k*32 + qd*8]);

    #pragma unroll
    for (int og = 0; og < 2; ++og) {
        const int o0 = (wave * 2 + og) * 16;        // 8 waves x 2 = 16 o-tiles
        short8 B[8];
        #pragma unroll
        for (int k = 0; k < 8; ++k)
            B[k] = *(const short8*)(W + (size_t)(o0 + m) * CDIM + k*32 + qd*8);
        floatx4 acc0 = {0,0,0,0}, acc1 = {0,0,0,0};
        #pragma unroll
        for (int k = 0; k < 8; ++k) {
            acc0 = __builtin_amdgcn_mfma_f32_16x16x32_bf16(A[0][k], B[k], acc0, 0, 0, 0);
            acc1 = __builtin_amdgcn_mfma_f32_16x16x32_bf16(A[1][k], B[k], acc1, 0, 0, 0);
        }
        const int o = o0 + (lane & 15), h = o >> 5, d = o & 31;
        const float bv_ = bias[o];
        #pragma unroll
        for (int rg = 0; rg < 4; ++rg) {
            const int p = m0 + (lane >> 4) * 4 + rg;
            dst[((size_t)(n*NHEAD + h)*HW + p)*HD + d]      = __float2bfloat16((acc0[rg] + bv_) * scale);
            dst[((size_t)(n*NHEAD + h)*HW + p + 16)*HD + d] = __float2bfloat16((acc1[rg] + bv_) * scale);
        }
    }
}

// ---------------- Kernel 3: full-MFMA fused local attention (rel in-kernel) -------
// Round-6 structure (146.0 us; setprio removed -- r8 measured it -3 us harmful).
// r8 counters: MfmaUtil 2%, VALUBusy 26%, HBM 10%, Occ 37% -> latency-bound.
// This round: T14 issue-early V^T staging -- half-0's V fragments preloaded to
// registers at kernel top (latency hides under rel+QK+softmax), half-1's issued
// right after half-0's ds_writes free the registers (hides under half-0 MFMA
// phases). +32 VGPR in flight (44 -> ~80, still under the 102 cap @5 blocks/CU).
// LDS map:
//   sP  [16][488] u16 : kk-space P                         (15,616 B)  @0
//   R2: sRel [16][248] -> sPw [16][264] u16                ( 8,448 B)  @15,616
//   R1: sMax/sSum f32[64] -> V^T/Rv^T [16][264] u16 -> sOh f32[1024]
//                                                          ( 8,448 B)  @24,064
#define SP_OFF    0
#define R2_OFF    15616
#define R1_OFF    24064
#define SMAX_OFF  24064
#define SSUM_OFF  24320
#define SMEM_SZ   32512

__global__ __launch_bounds__(256, 5) void attn_mfma(
    const __hip_bfloat16* __restrict__ qs, const __hip_bfloat16* __restrict__ ks,
    const __hip_bfloat16* __restrict__ vs,
    const short* __restrict__ rkwb, const short* __restrict__ rkbb,
    const __hip_bfloat16* __restrict__ relvT,   // [h][w][d]
    const int* __restrict__ flag,
    __hip_bfloat16* __restrict__ agg,           // [hw, n, 256]
    void* __restrict__ dout)
{
    __shared__ __align__(16) char smem[SMEM_SZ];
    short* sP   = (short*)(smem + SP_OFF);
    short* sRel = (short*)(smem + R2_OFF);   // alias: dead before sPw writes
    short* sPw  = (short*)(smem + R2_OFF);
    short* sB   = (short*)(smem + R1_OFF);   // V^T chunks / Rv^T
    float* sOh  = (float*)(smem + R1_OFF);   // O partials (after MFMA reads)
    float* sMax = (float*)(smem + SMAX_OFF); // alias into R1 (dead before sB writes)
    float* sSum = (float*)(smem + SSUM_OFF);

    const bool f32 = (*flag != 0);
    const int tid = threadIdx.x;
    const int wave = tid >> 6, lane = tid & 63;
    const int m = lane & 15, quad = lane >> 4;
    const int y = blockIdx.x / 3, tile3 = blockIdx.x % 3;
    const int x0 = (tile3 == 0) ? 0 : (tile3 == 1) ? 16 : 24;
    const int wlo = (tile3 == 2) ? 8 : 0;
    const int nh_ = blockIdx.y;
    const int h = nh_ & 7, n = nh_ >> 3;
    const size_t qb = (size_t)nh_ * HW;
    const size_t qrow0 = qb + (size_t)y * WDIM + x0;

    const short8 afrag = *(const short8*)((const short*)qs + (qrow0 + m) * HD + quad * 8);

    // ---- V^T staging pointers + HALF-0 PRELOAD (T14 issue-early) ----
    const short *c0p0 = nullptr, *c0p1 = nullptr, *c1p0 = nullptr, *c1p1 = nullptr;
    if (tid < 128) {
        const int kk0 = 2 * tid;
        const int r = kk0 >> 5, c = kk0 & 31;
        const int gky = min(max(y + r - 7, 0), WDIM - 1);
        const int gkx0 = min(max(x0 - 7 + c, 0), WDIM - 1);
        const int gkx1 = min(max(x0 - 7 + c + 1, 0), WDIM - 1);
        c0p0 = (const short*)vs + (qb + (size_t)gky * WDIM + gkx0) * HD;
        c0p1 = (const short*)vs + (qb + (size_t)gky * WDIM + gkx1) * HD;
    }
    if (tid < 112) {
        const int kk0 = 256 + 2 * tid;
        const int r = kk0 >> 5, c = kk0 & 31;
        const int gky = min(max(y + r - 7, 0), WDIM - 1);
        const int gkx0 = min(max(x0 - 7 + c, 0), WDIM - 1);
        const int gkx1 = min(max(x0 - 7 + c + 1, 0), WDIM - 1);
        c1p0 = (const short*)vs + (qb + (size_t)gky * WDIM + gkx0) * HD;
        c1p1 = (const short*)vs + (qb + (size_t)gky * WDIM + gkx1) * HD;
    }
    short8 v00, v01, v10, v11;   // chunk0 fragments (current half)
    short8 w00, w01, w10, w11;   // chunk1 fragments (current half)
    if (tid < 128) {
        v00 = *(const short8*)c0p0;       v01 = *(const short8*)c0p1;
        v10 = *(const short8*)(c0p0 + 8); v11 = *(const short8*)(c0p1 + 8);
    }
    if (tid < 112) {
        w00 = *(const short8*)c1p0;       w01 = *(const short8*)c1p1;
        w10 = *(const short8*)(c1p0 + 8); w11 = *(const short8*)(c1p1 + 8);
    }

    // ---- rel[qm][w] = T*(qs . rkw) + rkb via 15 MFMAs (w-tiles split across waves) ----
    for (int wt = wave; wt < 15; wt += 4) {
        const int w0 = wt * 16;
        const int wl = min(w0 + m, WS2 - 1);
        const short8 B = *(const short8*)(rkwb + ((size_t)h * WS2 + wl) * HD + quad * 8);
        floatx4 acc = {0.f, 0.f, 0.f, 0.f};
        acc = __builtin_amdgcn_mfma_f32_16x16x32_bf16(afrag, B, acc, 0, 0, 0);
        const int wcol = w0 + m;                  // D: col=lane&15, row=quad*4+rg
        if (wcol < WS2) {
            const float rb_ = bu2f(rkbb[(size_t)h * WS2 + wcol]);
            #pragma unroll
            for (int rg = 0; rg < 4; ++rg)
                sRel[(quad * 4 + rg) * RELSTR + wcol] = f2bu(acc[rg] * TSC + rb_);
        }
    }
    __syncthreads();

    // ---- S^T = K.Q^T + rel : D[row=key][col=query], lane owns query m ----
    float L[8][4];
    #pragma unroll
    for (int j = 0; j < 8; ++j)
        #pragma unroll
        for (int rg = 0; rg < 4; ++rg) L[j][rg] = -1e30f;

    #pragma unroll
    for (int j = 0; j < 8; ++j) {
        const int t = wave + 4 * j;
        if (t < 30) {
            const int r = t >> 1, c0_ = (t & 1) << 4;
            const int cc = c0_ + m;                 // key row this lane LOADS
            const int ky = y + r - 7, kxl = x0 - 7 + cc;
            const int gky = min(max(ky, 0), WDIM - 1), gkx = min(max(kxl, 0), WDIM - 1);
            const short8 kfrag = *(const short8*)((const short*)ks + (qb + (size_t)gky * WDIM + gkx) * HD + quad * 8);
            floatx4 s4 = {0.f, 0.f, 0.f, 0.f};
            s4 = __builtin_amdgcn_mfma_f32_16x16x32_bf16(kfrag, afrag, s4, 0, 0, 0);
            const bool kyok = (unsigned)ky < (unsigned)WDIM;
            #pragma unroll
            for (int rg = 0; rg < 4; ++rg) {
                const int kkc = c0_ + quad * 4 + rg;   // D row = key col 0..31
                const int kx = x0 - 7 + kkc;
                const int dx7 = kkc - m;
                if (kyok && (unsigned)kx < (unsigned)WDIM && (unsigned)dx7 < 15u)
                    L[j][rg] = s4[rg] + bu2f(sRel[m * RELSTR + r * 15 + dx7]);
            }
        }
    }

    // ---- block softmax: lane owns one query; in-lane reduce + 2 shfl + 4-wave LDS ----
    float mx = L[0][0];
    #pragma unroll
    for (int j = 0; j < 8; ++j)
        #pragma unroll
        for (int rg = 0; rg < 4; ++rg) mx = fmaxf(mx, L[j][rg]);
    mx = fmaxf(mx, __shfl_xor(mx, 16));
    mx = fmaxf(mx, __shfl_xor(mx, 32));
    if (lane < 16) sMax[lane * 4 + wave] = mx;
    __syncthreads();
    const float4 vM = *(const float4*)&sMax[m * 4];
    const float M = fmaxf(fmaxf(vM.x, vM.y), fmaxf(vM.z, vM.w));
    float sm = 0.f;
    #pragma unroll
    for (int j = 0; j < 8; ++j)
        #pragma unroll
        for (int rg = 0; rg < 4; ++rg) { L[j][rg] = __expf(L[j][rg] - M); sm += L[j][rg]; }
    sm += __shfl_xor(sm, 16);
    sm += __shfl_xor(sm, 32);
    if (lane < 16) sSum[lane * 4 + wave] = sm;
    __syncthreads();
    const float4 vS = *(const float4*)&sSum[m * 4];
    const float inv = 1.f / (vS.x + vS.y + vS.z + vS.w);

    // ---- zero sPw gap/pad cols: r*16+15 (r=0..14) and 240..263 (39 cols/row) ----
    for (int e = tid; e < 16 * 39; e += 256) {
        const int row = e / 39, idx = e - row * 39;
        const int c = (idx < 15) ? idx * 16 + 15 : 240 + (idx - 15);
        sPw[row * 264 + c] = 0;
    }

    // ---- write P: sP packed 8B (4 consecutive kk); sPw window layout r*16+dx7 ----
    #pragma unroll
    for (int j = 0; j < 8; ++j) {
        const int t = wave + 4 * j;
        if (t < 30) {
            const int r = t >> 1, c0_ = (t & 1) << 4;
            const int kb = c0_ + quad * 4;
            short4v pk;
            #pragma unroll
            for (int rg = 0; rg < 4; ++rg) pk[rg] = f2bu(L[j][rg] * inv);  // exact 0 when invalid
            *(short4v*)(sP + m * 488 + r * 32 + kb) = pk;
            #pragma unroll
            for (int rg = 0; rg < 4; ++rg) {
                const int dx7 = kb + rg - m;
                if ((unsigned)dx7 < 15u) sPw[m * 264 + r * 16 + dx7] = pk[rg];
            }
        }
    }
    __syncthreads();

    // ---- coalesced attn_out copy from window-space P (col w -> kcol r*16+dx7) ----
    #pragma unroll
    for (int rr = 0; rr < 4; ++rr) {
        const int qm = wave * 4 + rr;
        if (qm >= wlo) {
            const size_t obase = (size_t)PROJ + (qrow0 + qm) * WS2;
            #pragma unroll
            for (int c = 0; c < 4; ++c) {
                const int col = lane + 64 * c;
                if (col < WS2) {
                    const int rq = col / 15, dxq = col - rq * 15;
                    st_out(dout, obase + col, bu2f(sPw[qm * 264 + rq * 16 + dxq]), f32);
                }
            }
        }
    }

    // ---- PV + rel_v GEMMs, d in halves of 16; V^T staged from preloaded regs ----
    for (int half = 0; half < 2; ++half) {
        __syncthreads();
        {   // write chunk0 (kk rows 0..7) from preloaded regs
            if (tid < 128) {
                unsigned* dstw = (unsigned*)sB;
                #pragma unroll
                for (int dd = 0; dd < 8; ++dd) dstw[dd * 132 + tid] = pk2(v00[dd], v01[dd]);
                #pragma unroll
                for (int dd = 0; dd < 8; ++dd) dstw[(dd + 8) * 132 + tid] = pk2(v10[dd], v11[dd]);
            }
        }
        if (half == 0 && tid < 128) {   // issue half-1 chunk0 loads (hide under MFMAs)
            v00 = *(const short8*)(c0p0 + 16); v01 = *(const short8*)(c0p1 + 16);
            v10 = *(const short8*)(c0p0 + 24); v11 = *(const short8*)(c0p1 + 24);
        }
        __syncthreads();
        floatx4 acc = {0.f, 0.f, 0.f, 0.f};
        const int h16 = half << 4;
        for (int u = wave; u < 8; u += 4) {          // u = wave, wave+4
            const short8 Af = *(const short8*)(sP + m * 488 + u * 32 + quad * 8);
            const short8 Bf = *(const short8*)(sB + m * 264 + u * 32 + quad * 8);
            acc = __builtin_amdgcn_mfma_f32_16x16x32_bf16(Af, Bf, acc, 0, 0, 0);
        }
        __syncthreads();
        {   // write chunk1 (kk rows 8..14) from preloaded regs
            if (tid < 112) {
                unsigned* dstw = (unsigned*)sB;
                #pragma unroll
                for (int dd = 0; dd < 8; ++dd) dstw[dd * 132 + tid] = pk2(w00[dd], w01[dd]);
                #pragma unroll
                for (int dd = 0; dd < 8; ++dd) dstw[(dd + 8) * 132 + tid] = pk2(w10[dd], w11[dd]);
            }
        }
        if (half == 0 && tid < 112) {   // issue half-1 chunk1 loads
            w00 = *(const short8*)(c1p0 + 16); w01 = *(const short8*)(c1p1 + 16);
            w10 = *(const short8*)(c1p0 + 24); w11 = *(const short8*)(c1p1 + 24);
        }
        __syncthreads();
        for (int u = 8 + wave; u < 15; u += 4) {     // u = 8+wave, 12+wave
            const short8 Af = *(const short8*)(sP + m * 488 + u * 32 + quad * 8);
            const short8 Bf = *(const short8*)(sB + m * 264 + (u - 8) * 32 + quad * 8);
            acc = __builtin_amdgcn_mfma_f32_16x16x32_bf16(Af, Bf, acc, 0, 0, 0);
        }
        __syncthreads();
        {   // stage Rv^T rows [d-half][kcol], stride 264 shorts; kcol = r*16+dx7,
            // gap cols (dx7==15) and kcol>=240 zero
            unsigned* dstw = (unsigned*)sB;
            for (int p = tid; p < 132; p += 256) {
                short8 a0 = {0,0,0,0,0,0,0,0}, a1 = a0, b0 = a0, b1 = a0;
                if (p < 120) {
                    const int kcol0 = 2 * p;
                    const int r = kcol0 >> 4, dx = kcol0 & 15;   // dx even <= 14
                    const int w0 = r * 15 + dx;                   // <= 224
                    const short* rp = (const short*)relvT + ((size_t)h * WS2 + w0) * HD + h16;
                    a0 = *(const short8*)rp; a1 = *(const short8*)(rp + 8);
                    if (dx < 14) {   // kcol0+1 in-window; dx==14 -> gap col, stays 0
                        const short* rq = (const short*)relvT + ((size_t)h * WS2 + w0 + 1) * HD + h16;
                        b0 = *(const short8*)rq; b1 = *(const short8*)(rq + 8);
                    }
                }
                #pragma unroll
                for (int dd = 0; dd < 8; ++dd) dstw[dd * 132 + p] = pk2(a0[dd], b0[dd]);
                #pragma unroll
                for (int dd = 0; dd < 8; ++dd) dstw[(dd + 8) * 132 + p] = pk2(a1[dd], b1[dd]);
            }
        }
        __syncthreads();
        for (int u = wave; u < 8; u += 4) {
            const short8 Af = *(const short8*)(sPw + m * 264 + u * 32 + quad * 8);
            const short8 Bf = *(const short8*)(sB + m * 264 + u * 32 + quad * 8);
            acc = __builtin_amdgcn_mfma_f32_16x16x32_bf16(Af, Bf, acc, 0, 0, 0);
        }
        __syncthreads();
        #pragma unroll
        for (int rg = 0; rg < 4; ++rg)
            sOh[wave * 256 + (quad * 4 + rg) * 16 + m] = acc[rg];
        __syncthreads();
        {
            const int qq = tid >> 4, dd = tid & 15;
            const float s = sOh[tid] + sOh[256 + tid] + sOh[512 + tid] + sOh[768 + tid];
            if (qq >= wlo) {
                const size_t i = (size_t)y * WDIM + x0 + qq;
                agg[(i * NB + n) * CDIM + h * HD + h16 + dd] = __float2bfloat16(s);
            }
        }
    }
}

// ---------------- Kernel 4: output projection via MFMA (A-frags reused 8x) ------
__global__ __launch_bounds__(256) void out_mfma(
    const __hip_bfloat16* __restrict__ agg, const short* __restrict__ Wpb,
    const float* __restrict__ bpf, const int* __restrict__ flag,
    void* __restrict__ dout)
{
    const bool f32 = (*flag != 0);
    const int wave = threadIdx.x >> 6, lane = threadIdx.x & 63;
    const int rb0 = blockIdx.x << 4;                 // 200 blocks x 16 rows = 3200
    const int m = lane & 15, qd = lane >> 4;

    const __hip_bfloat16* arow = agg + (size_t)(rb0 + m) * CDIM + qd * 8;
    short8 A[8];
    #pragma unroll
    for (int k = 0; k < 8; ++k)
        A[k] = *(const short8*)(arow + k * 32);

    #pragma unroll
    for (int p = 0; p < 2; ++p) {
        const int o0 = wave * 64 + p * 32;           // pair covers o0..o0+31
        floatx4 acc0 = {0.f, 0.f, 0.f, 0.f}, acc1 = {0.f, 0.f, 0.f, 0.f};
        #pragma unroll
        for (int k = 0; k < 8; ++k) {
            short8 b0 = *(const short8*)(Wpb + (size_t)(o0 + m) * CDIM + k * 32 + qd * 8);
            short8 b1 = *(const short8*)(Wpb + (size_t)(o0 + 16 + m) * CDIM + k * 32 + qd * 8);
            acc0 = __builtin_amdgcn_mfma_f32_16x16x32_bf16(A[k], b0, acc0, 0, 0, 0);
            acc1 = __builtin_amdgcn_mfma_f32_16x16x32_bf16(A[k], b1, acc1, 0, 0, 0);
        }
        const int oa = o0 + (lane & 15), ob = oa + 16;
        const float ba_ = bpf[oa];
        const float bb_ = bpf[ob];
        #pragma unroll
        for (int rg = 0; rg < 4; ++rg) {
            const int rb = rb0 + (lane >> 4) * 4 + rg;
            st_out(dout, (size_t)rb * CDIM + oa, acc0[rg] + ba_, f32);
            st_out(dout, (size_t)rb * CDIM + ob, acc1[rg] + bb_, f32);
        }
    }
}

extern "C" void kernel_launch(void* const* d_in, const int* in_sizes, int n_in,
                              void* d_out, int out_size, void* d_ws, size_t ws_size,
                              hipStream_t stream)
{
    const void* q   = d_in[0];
    const void* k   = d_in[1];
    const void* v   = d_in[2];
    const void* Wq  = d_in[3];
    const void* bq  = d_in[4];
    const void* Wk  = d_in[5];
    const void* bk  = d_in[6];
    const void* Wv  = d_in[7];
    const void* bv  = d_in[8];
    const void* rkw = d_in[9];
    const void* rkb = d_in[10];
    const void* rlv = d_in[11];
    const void* Wp  = d_in[12];
    const void* bp  = d_in[13];

    // ws layout (7.32 MB):
    //   flag(64B) | relvT(115200B) | qs | ks | vs | agg (PROJ bf16 each)
    //   | Wqb|Wkb|Wvb|Wpb (131072B each) | rkwb(115200B) | rkbb(3600B)
    //   | bqf|bkf|bvf|bpf (1024B each, fp32)
    char* wsb = (char*)d_ws;
    int* flag = (int*)wsb;
    __hip_bfloat16* relvT = (__hip_bfloat16*)(wsb + 64);
    __hip_bfloat16* qs    = (__hip_bfloat16*)(wsb + 64 + 115200);
    __hip_bfloat16* ks    = qs + PROJ;
    __hip_bfloat16* vs    = ks + PROJ;
    __hip_bfloat16* agg   = vs + PROJ;
    __hip_bfloat16* Wqb   = (__hip_bfloat16*)(wsb + 6668864);
    __hip_bfloat16* Wkb   = Wqb + CDIM * CDIM;
    __hip_bfloat16* Wvb   = Wkb + CDIM * CDIM;
    __hip_bfloat16* Wpb   = Wvb + CDIM * CDIM;
    __hip_bfloat16* rkwb  = (__hip_bfloat16*)(wsb + 7193152);
    __hip_bfloat16* rkbb  = (__hip_bfloat16*)(wsb + 7308352);
    float* bqf = (float*)(wsb + 7311952);
    float* bkf = bqf + CDIM;
    float* bvf = bkf + CDIM;
    float* bpf = bvf + CDIM;

    prep_kernel<<<128, 256, 0, stream>>>(q, rlv, Wq, Wk, Wv, Wp, bq, bk, bv, bp,
                                         rkw, rkb, flag, relvT,
                                         Wqb, Wkb, Wvb, Wpb, bqf, bkf, bvf, bpf,
                                         rkwb, rkbb);
    proj_fused<<<dim3(50, 2, 3), 512, 0, stream>>>(q, k, v, Wqb, bqf, Wkb, bkf,
                                                   Wvb, bvf, flag, qs, ks, vs);
    attn_mfma<<<dim3(120, 16), 256, 0, stream>>>(qs, ks, vs, (const short*)rkwb,
                                                 (const short*)rkbb, relvT, flag,
                                                 agg, d_out);
    out_mfma<<<200, 256, 0, stream>>>(agg, (const short*)Wpb, bpf, flag, d_out);
}

// Round 10
// 149.979 us; speedup vs baseline: 1.0360x; 1.0360x over previous
//
#include <hip/hip_runtime.h>
#include <hip/hip_bf16.h>

#define HW    1600
#define NB    2
#define NHEAD 8
#define HD    32
#define WS2   225
#define WDIM  40
#define CDIM  256
#define PROJ  819200                 // NB*NHEAD*HW*HD elements
#define RELSTR 248                   // LDS rel row stride (multiple of 8 shorts = 16B)
#define TSC   5.656854249492381f     // sqrt(32)

typedef __attribute__((ext_vector_type(8))) short short8;
typedef __attribute__((ext_vector_type(4))) short short4v;
typedef __attribute__((ext_vector_type(4))) float floatx4;

static __device__ __forceinline__ float bu2f(short u) {
    return __uint_as_float(((unsigned)(unsigned short)u) << 16);
}
static __device__ __forceinline__ short f2bu(float f) {
    __hip_bfloat16 h = __float2bfloat16(f);
    short s; __builtin_memcpy(&s, &h, 2); return s;
}
static __device__ __forceinline__ unsigned pk2(short a, short b) {
    return (unsigned)(unsigned short)a | ((unsigned)(unsigned short)b << 16);
}
static __device__ __forceinline__ float ldf(const void* p, size_t i, bool f32) {
    return f32 ? ((const float*)p)[i] : __bfloat162float(((const __hip_bfloat16*)p)[i]);
}
static __device__ __forceinline__ void st_out(void* p, size_t i, float v, bool f32) {
    if (f32) ((float*)p)[i] = v;
    else     ((__hip_bfloat16*)p)[i] = __float2bfloat16(v);
}
static __device__ __forceinline__ short8 ld8bf(const void* p, size_t i, bool f32) {
    if (!f32) return *(const short8*)((const __hip_bfloat16*)p + i);
    const float* f = (const float*)p + i;
    short8 r;
    #pragma unroll
    for (int t = 0; t < 8; ++t) r[t] = f2bu(f[t]);
    return r;
}

// ---------------- Kernel 1: fused dtype-detect + projection GEMM + conversions ----
// grid (50,2,4), 512 threads. Every block self-detects dtype from q (no cross-
// block dependency). z<3: q/k/v projection GEMM reading RAW Wq/Wk/Wv/biases
// (ld8bf per fragment -- same RNE rounding as the old prep conversion, bit-
// identical results). z==3 (100 blocks): grid-stride conversions consumed by
// the LATER attn/out kernels (relvT, rkwb, rkbb, Wpb, bpf) + flag publish.
// This removes the former prep kernel (one fewer graph node).
__global__ __launch_bounds__(512) void proj_fused(
    const void* __restrict__ xq, const void* __restrict__ xk, const void* __restrict__ xv,
    const void* __restrict__ Wq, const void* __restrict__ bq,
    const void* __restrict__ Wk, const void* __restrict__ bk,
    const void* __restrict__ Wv, const void* __restrict__ bv,
    const void* __restrict__ rkw, const void* __restrict__ rkb,
    const void* __restrict__ relv, const void* __restrict__ Wp,
    const void* __restrict__ bp,
    int* __restrict__ flag, __hip_bfloat16* __restrict__ relvT,
    __hip_bfloat16* __restrict__ rkwb, __hip_bfloat16* __restrict__ rkbb,
    __hip_bfloat16* __restrict__ Wpb, float* __restrict__ bpf,
    __hip_bfloat16* __restrict__ qs, __hip_bfloat16* __restrict__ ks,
    __hip_bfloat16* __restrict__ vs)
{
    __shared__ short xt[32][264];
    __shared__ int sbad;
    const int tid = threadIdx.x;
    if (tid == 0) sbad = 0;
    __syncthreads();
    {
        int bad = 0;
        const __hip_bfloat16* qbb = (const __hip_bfloat16*)xq;
        for (int i = tid; i < 4096; i += 512) {
            float v = __bfloat162float(qbb[i]);
            if (!(v > -1e6f && v < 1e6f)) bad = 1;   // fp32-misread garbage / NaN
        }
        if (bad) sbad = 1;
    }
    __syncthreads();
    const bool f32 = (sbad != 0);

    if (blockIdx.z == 3) {
        // conversion slice (outputs used only by later kernels)
        if (blockIdx.x == 0 && blockIdx.y == 0 && tid == 0) *flag = sbad;
        const int gid = (blockIdx.y * 50 + blockIdx.x) * 512 + tid;
        const int gsz = 100 * 512;
        for (int e = gid; e < NHEAD * WS2 * HD; e += gsz) {
            const int h = e / (WS2 * HD), idx = e - h * (WS2 * HD);
            const int w = idx >> 5, d = idx & 31;
            relvT[e] = __float2bfloat16(ldf(relv, ((size_t)h * HD + d) * WS2 + w, f32));
        }
        for (int e = gid; e < NHEAD * WS2 * HD; e += gsz)
            rkwb[e] = __float2bfloat16(ldf(rkw, e, f32));
        for (int e = gid; e < NHEAD * WS2; e += gsz)
            rkbb[e] = __float2bfloat16(ldf(rkb, e, f32));
        for (int e = gid; e < CDIM * CDIM; e += gsz)
            Wpb[e] = __float2bfloat16(ldf(Wp, e, f32));
        for (int e = gid; e < CDIM; e += gsz)
            bpf[e] = ldf(bp, e, f32);
        return;
    }

    const int m0 = blockIdx.x * 32;
    const int n  = blockIdx.y;
    const int t  = blockIdx.z;
    const void* x; const void* W; const void* bias; __hip_bfloat16* dst; float scale;
    if (t == 0)      { x = xq; W = Wq; bias = bq; dst = qs; scale = 0.17677669529663687f; }
    else if (t == 1) { x = xk; W = Wk; bias = bk; dst = ks; scale = 1.f; }
    else             { x = xv; W = Wv; bias = bv; dst = vs; scale = 1.f; }

    {
        const int c  = tid & 255;
        const int gh = tid >> 8;                    // which 16-row half of the tile
        const size_t xb = ((size_t)n * CDIM + c) * HW + m0 + gh * 16;
        if (f32) {
            const float* xr = (const float*)x + xb;
            #pragma unroll
            for (int g = 0; g < 4; ++g) {
                float4 f = *(const float4*)(xr + g * 4);
                xt[gh*16 + g*4+0][c] = f2bu(f.x); xt[gh*16 + g*4+1][c] = f2bu(f.y);
                xt[gh*16 + g*4+2][c] = f2bu(f.z); xt[gh*16 + g*4+3][c] = f2bu(f.w);
            }
        } else {
            const __hip_bfloat16* xr = (const __hip_bfloat16*)x + xb;
            short8 s0 = *(const short8*)(xr);
            short8 s1 = *(const short8*)(xr + 8);
            #pragma unroll
            for (int u = 0; u < 8; ++u) {
                xt[gh*16 + u][c]     = s0[u];
                xt[gh*16 + 8 + u][c] = s1[u];
            }
        }
    }
    __syncthreads();

    const int wave = tid >> 6, lane = tid & 63;     // wave 0..7
    const int m = lane & 15, qd = lane >> 4;

    short8 A[2][8];
    #pragma unroll
    for (int mt = 0; mt < 2; ++mt)
        #pragma unroll
        for (int k = 0; k < 8; ++k)
            A[mt][k] = *(const short8*)(&xt[mt*16 + m][k*32 + qd*8]);

    #pragma unroll
    for (int og = 0; og < 2; ++og) {
        const int o0 = (wave * 2 + og) * 16;        // 8 waves x 2 = 16 o-tiles
        short8 B[8];
        #pragma unroll
        for (int k = 0; k < 8; ++k)
            B[k] = ld8bf(W, (size_t)(o0 + m) * CDIM + k*32 + qd*8, f32);
        floatx4 acc0 = {0,0,0,0}, acc1 = {0,0,0,0};
        #pragma unroll
        for (int k = 0; k < 8; ++k) {
            acc0 = __builtin_amdgcn_mfma_f32_16x16x32_bf16(A[0][k], B[k], acc0, 0, 0, 0);
            acc1 = __builtin_amdgcn_mfma_f32_16x16x32_bf16(A[1][k], B[k], acc1, 0, 0, 0);
        }
        const int o = o0 + (lane & 15), h = o >> 5, d = o & 31;
        const float bv_ = ldf(bias, (size_t)o, f32);
        #pragma unroll
        for (int rg = 0; rg < 4; ++rg) {
            const int p = m0 + (lane >> 4) * 4 + rg;
            dst[((size_t)(n*NHEAD + h)*HW + p)*HD + d]      = __float2bfloat16((acc0[rg] + bv_) * scale);
            dst[((size_t)(n*NHEAD + h)*HW + p + 16)*HD + d] = __float2bfloat16((acc1[rg] + bv_) * scale);
        }
    }
}

// ---------------- Kernel 2: full-MFMA fused local attention (round-6 verified) ----
// 146.0 us structure, byte-identical: QK operand-swapped, 31.75 KB LDS ->
// 5 blocks/CU, chunked V^T staging, coalesced attn_out copy phase.
// (r7 direct-store +10us, r8 setprio +3us, r9 T14 preload +9us: all reverted.)
// LDS map:
//   sP  [16][488] u16 : kk-space P                         (15,616 B)  @0
//   R2: sRel [16][248] -> sPw [16][264] u16                ( 8,448 B)  @15,616
//   R1: sMax/sSum f32[64] -> V^T/Rv^T [16][264] u16 -> sOh f32[1024]
//                                                          ( 8,448 B)  @24,064
#define SP_OFF    0
#define R2_OFF    15616
#define R1_OFF    24064
#define SMAX_OFF  24064
#define SSUM_OFF  24320
#define SMEM_SZ   32512

__global__ __launch_bounds__(256, 5) void attn_mfma(
    const __hip_bfloat16* __restrict__ qs, const __hip_bfloat16* __restrict__ ks,
    const __hip_bfloat16* __restrict__ vs,
    const short* __restrict__ rkwb, const short* __restrict__ rkbb,
    const __hip_bfloat16* __restrict__ relvT,   // [h][w][d]
    const int* __restrict__ flag,
    __hip_bfloat16* __restrict__ agg,           // [hw, n, 256]
    void* __restrict__ dout)
{
    __shared__ __align__(16) char smem[SMEM_SZ];
    short* sP   = (short*)(smem + SP_OFF);
    short* sRel = (short*)(smem + R2_OFF);   // alias: dead before sPw writes
    short* sPw  = (short*)(smem + R2_OFF);
    short* sB   = (short*)(smem + R1_OFF);   // V^T chunks / Rv^T
    float* sOh  = (float*)(smem + R1_OFF);   // O partials (after MFMA reads)
    float* sMax = (float*)(smem + SMAX_OFF); // alias into R1 (dead before sB writes)
    float* sSum = (float*)(smem + SSUM_OFF);

    const bool f32 = (*flag != 0);
    const int tid = threadIdx.x;
    const int wave = tid >> 6, lane = tid & 63;
    const int m = lane & 15, quad = lane >> 4;
    const int y = blockIdx.x / 3, tile3 = blockIdx.x % 3;
    const int x0 = (tile3 == 0) ? 0 : (tile3 == 1) ? 16 : 24;
    const int wlo = (tile3 == 2) ? 8 : 0;
    const int nh_ = blockIdx.y;
    const int h = nh_ & 7, n = nh_ >> 3;
    const size_t qb = (size_t)nh_ * HW;
    const size_t qrow0 = qb + (size_t)y * WDIM + x0;

    const short8 afrag = *(const short8*)((const short*)qs + (qrow0 + m) * HD + quad * 8);

    // ---- rel[qm][w] = T*(qs . rkw) + rkb via 15 MFMAs (w-tiles split across waves) ----
    for (int wt = wave; wt < 15; wt += 4) {
        const int w0 = wt * 16;
        const int wl = min(w0 + m, WS2 - 1);
        const short8 B = *(const short8*)(rkwb + ((size_t)h * WS2 + wl) * HD + quad * 8);
        floatx4 acc = {0.f, 0.f, 0.f, 0.f};
        acc = __builtin_amdgcn_mfma_f32_16x16x32_bf16(afrag, B, acc, 0, 0, 0);
        const int wcol = w0 + m;                  // D: col=lane&15, row=quad*4+rg
        if (wcol < WS2) {
            const float rb_ = bu2f(rkbb[(size_t)h * WS2 + wcol]);
            #pragma unroll
            for (int rg = 0; rg < 4; ++rg)
                sRel[(quad * 4 + rg) * RELSTR + wcol] = f2bu(acc[rg] * TSC + rb_);
        }
    }
    __syncthreads();

    // ---- S^T = K.Q^T + rel : D[row=key][col=query], lane owns query m ----
    float L[8][4];
    #pragma unroll
    for (int j = 0; j < 8; ++j)
        #pragma unroll
        for (int rg = 0; rg < 4; ++rg) L[j][rg] = -1e30f;

    #pragma unroll
    for (int j = 0; j < 8; ++j) {
        const int t = wave + 4 * j;
        if (t < 30) {
            const int r = t >> 1, c0_ = (t & 1) << 4;
            const int cc = c0_ + m;                 // key row this lane LOADS
            const int ky = y + r - 7, kxl = x0 - 7 + cc;
            const int gky = min(max(ky, 0), WDIM - 1), gkx = min(max(kxl, 0), WDIM - 1);
            const short8 kfrag = *(const short8*)((const short*)ks + (qb + (size_t)gky * WDIM + gkx) * HD + quad * 8);
            floatx4 s4 = {0.f, 0.f, 0.f, 0.f};
            s4 = __builtin_amdgcn_mfma_f32_16x16x32_bf16(kfrag, afrag, s4, 0, 0, 0);
            const bool kyok = (unsigned)ky < (unsigned)WDIM;
            #pragma unroll
            for (int rg = 0; rg < 4; ++rg) {
                const int kkc = c0_ + quad * 4 + rg;   // D row = key col 0..31
                const int kx = x0 - 7 + kkc;
                const int dx7 = kkc - m;
                if (kyok && (unsigned)kx < (unsigned)WDIM && (unsigned)dx7 < 15u)
                    L[j][rg] = s4[rg] + bu2f(sRel[m * RELSTR + r * 15 + dx7]);
            }
        }
    }

    // ---- block softmax: lane owns one query; in-lane reduce + 2 shfl + 4-wave LDS ----
    float mx = L[0][0];
    #pragma unroll
    for (int j = 0; j < 8; ++j)
        #pragma unroll
        for (int rg = 0; rg < 4; ++rg) mx = fmaxf(mx, L[j][rg]);
    mx = fmaxf(mx, __shfl_xor(mx, 16));
    mx = fmaxf(mx, __shfl_xor(mx, 32));
    if (lane < 16) sMax[lane * 4 + wave] = mx;
    __syncthreads();
    const float4 vM = *(const float4*)&sMax[m * 4];
    const float M = fmaxf(fmaxf(vM.x, vM.y), fmaxf(vM.z, vM.w));
    float sm = 0.f;
    #pragma unroll
    for (int j = 0; j < 8; ++j)
        #pragma unroll
        for (int rg = 0; rg < 4; ++rg) { L[j][rg] = __expf(L[j][rg] - M); sm += L[j][rg]; }
    sm += __shfl_xor(sm, 16);
    sm += __shfl_xor(sm, 32);
    if (lane < 16) sSum[lane * 4 + wave] = sm;
    __syncthreads();
    const float4 vS = *(const float4*)&sSum[m * 4];
    const float inv = 1.f / (vS.x + vS.y + vS.z + vS.w);

    // ---- zero sPw gap/pad cols: r*16+15 (r=0..14) and 240..263 (39 cols/row) ----
    for (int e = tid; e < 16 * 39; e += 256) {
        const int row = e / 39, idx = e - row * 39;
        const int c = (idx < 15) ? idx * 16 + 15 : 240 + (idx - 15);
        sPw[row * 264 + c] = 0;
    }

    // ---- write P: sP packed 8B (4 consecutive kk); sPw window layout r*16+dx7 ----
    #pragma unroll
    for (int j = 0; j < 8; ++j) {
        const int t = wave + 4 * j;
        if (t < 30) {
            const int r = t >> 1, c0_ = (t & 1) << 4;
            const int kb = c0_ + quad * 4;
            short4v pk;
            #pragma unroll
            for (int rg = 0; rg < 4; ++rg) pk[rg] = f2bu(L[j][rg] * inv);  // exact 0 when invalid
            *(short4v*)(sP + m * 488 + r * 32 + kb) = pk;
            #pragma unroll
            for (int rg = 0; rg < 4; ++rg) {
                const int dx7 = kb + rg - m;
                if ((unsigned)dx7 < 15u) sPw[m * 264 + r * 16 + dx7] = pk[rg];
            }
        }
    }
    __syncthreads();

    // ---- coalesced attn_out copy from window-space P (col w -> kcol r*16+dx7) ----
    #pragma unroll
    for (int rr = 0; rr < 4; ++rr) {
        const int qm = wave * 4 + rr;
        if (qm >= wlo) {
            const size_t obase = (size_t)PROJ + (qrow0 + qm) * WS2;
            #pragma unroll
            for (int c = 0; c < 4; ++c) {
                const int col = lane + 64 * c;
                if (col < WS2) {
                    const int rq = col / 15, dxq = col - rq * 15;
                    st_out(dout, obase + col, bu2f(sPw[qm * 264 + rq * 16 + dxq]), f32);
                }
            }
        }
    }

    // ---- PV + rel_v GEMMs, d in halves of 16; V^T staged in two kk-chunks ----
    for (int half = 0; half < 2; ++half) {
        __syncthreads();
        const int h16 = half << 4;
        {   // stage V^T chunk0: kk rows 0..7 (kk 0..255), 128 pair-items
            if (tid < 128) {
                unsigned* dstw = (unsigned*)sB;
                const int kk0 = 2 * tid;
                const int r = kk0 >> 5, c = kk0 & 31;
                const int gky = min(max(y + r - 7, 0), WDIM - 1);
                const int gkx0 = min(max(x0 - 7 + c, 0), WDIM - 1);
                const int gkx1 = min(max(x0 - 7 + c + 1, 0), WDIM - 1);
                const short* v0 = (const short*)vs + (qb + (size_t)gky * WDIM + gkx0) * HD + h16;
                const short* v1 = (const short*)vs + (qb + (size_t)gky * WDIM + gkx1) * HD + h16;
                const short8 a0 = *(const short8*)v0, b0 = *(const short8*)v1;
                const short8 a1 = *(const short8*)(v0 + 8), b1 = *(const short8*)(v1 + 8);
                #pragma unroll
                for (int dd = 0; dd < 8; ++dd) dstw[dd * 132 + tid] = pk2(a0[dd], b0[dd]);
                #pragma unroll
                for (int dd = 0; dd < 8; ++dd) dstw[(dd + 8) * 132 + tid] = pk2(a1[dd], b1[dd]);
            }
        }
        __syncthreads();
        floatx4 acc = {0.f, 0.f, 0.f, 0.f};
        for (int u = wave; u < 8; u += 4) {          // u = wave, wave+4
            const short8 Af = *(const short8*)(sP + m * 488 + u * 32 + quad * 8);
            const short8 Bf = *(const short8*)(sB + m * 264 + u * 32 + quad * 8);
            acc = __builtin_amdgcn_mfma_f32_16x16x32_bf16(Af, Bf, acc, 0, 0, 0);
        }
        __syncthreads();
        {   // stage V^T chunk1: kk rows 8..14 (kk 256..479), 112 pair-items
            if (tid < 112) {
                unsigned* dstw = (unsigned*)sB;
                const int kk0 = 256 + 2 * tid;
                const int r = kk0 >> 5, c = kk0 & 31;
                const int gky = min(max(y + r - 7, 0), WDIM - 1);
                const int gkx0 = min(max(x0 - 7 + c, 0), WDIM - 1);
                const int gkx1 = min(max(x0 - 7 + c + 1, 0), WDIM - 1);
                const short* v0 = (const short*)vs + (qb + (size_t)gky * WDIM + gkx0) * HD + h16;
                const short* v1 = (const short*)vs + (qb + (size_t)gky * WDIM + gkx1) * HD + h16;
                const short8 a0 = *(const short8*)v0, b0 = *(const short8*)v1;
                const short8 a1 = *(const short8*)(v0 + 8), b1 = *(const short8*)(v1 + 8);
                #pragma unroll
                for (int dd = 0; dd < 8; ++dd) dstw[dd * 132 + tid] = pk2(a0[dd], b0[dd]);
                #pragma unroll
                for (int dd = 0; dd < 8; ++dd) dstw[(dd + 8) * 132 + tid] = pk2(a1[dd], b1[dd]);
            }
        }
        __syncthreads();
        for (int u = 8 + wave; u < 15; u += 4) {     // u = 8+wave, 12+wave
            const short8 Af = *(const short8*)(sP + m * 488 + u * 32 + quad * 8);
            const short8 Bf = *(const short8*)(sB + m * 264 + (u - 8) * 32 + quad * 8);
            acc = __builtin_amdgcn_mfma_f32_16x16x32_bf16(Af, Bf, acc, 0, 0, 0);
        }
        __syncthreads();
        {   // stage Rv^T rows [d-half][kcol], stride 264 shorts; kcol = r*16+dx7,
            // gap cols (dx7==15) and kcol>=240 zero
            unsigned* dstw = (unsigned*)sB;
            for (int p = tid; p < 132; p += 256) {
                short8 a0 = {0,0,0,0,0,0,0,0}, a1 = a0, b0 = a0, b1 = a0;
                if (p < 120) {
                    const int kcol0 = 2 * p;
                    const int r = kcol0 >> 4, dx = kcol0 & 15;   // dx even <= 14
                    const int w0 = r * 15 + dx;                   // <= 224
                    const short* rp = (const short*)relvT + ((size_t)h * WS2 + w0) * HD + h16;
                    a0 = *(const short8*)rp; a1 = *(const short8*)(rp + 8);
                    if (dx < 14) {   // kcol0+1 in-window; dx==14 -> gap col, stays 0
                        const short* rq = (const short*)relvT + ((size_t)h * WS2 + w0 + 1) * HD + h16;
                        b0 = *(const short8*)rq; b1 = *(const short8*)(rq + 8);
                    }
                }
                #pragma unroll
                for (int dd = 0; dd < 8; ++dd) dstw[dd * 132 + p] = pk2(a0[dd], b0[dd]);
                #pragma unroll
                for (int dd = 0; dd < 8; ++dd) dstw[(dd + 8) * 132 + p] = pk2(a1[dd], b1[dd]);
            }
        }
        __syncthreads();
        for (int u = wave; u < 8; u += 4) {
            const short8 Af = *(const short8*)(sPw + m * 264 + u * 32 + quad * 8);
            const short8 Bf = *(const short8*)(sB + m * 264 + u * 32 + quad * 8);
            acc = __builtin_amdgcn_mfma_f32_16x16x32_bf16(Af, Bf, acc, 0, 0, 0);
        }
        __syncthreads();
        #pragma unroll
        for (int rg = 0; rg < 4; ++rg)
            sOh[wave * 256 + (quad * 4 + rg) * 16 + m] = acc[rg];
        __syncthreads();
        {
            const int qq = tid >> 4, dd = tid & 15;
            const float s = sOh[tid] + sOh[256 + tid] + sOh[512 + tid] + sOh[768 + tid];
            if (qq >= wlo) {
                const size_t i = (size_t)y * WDIM + x0 + qq;
                agg[(i * NB + n) * CDIM + h * HD + h16 + dd] = __float2bfloat16(s);
            }
        }
    }
}

// ---------------- Kernel 3: output projection via MFMA (A-frags reused 8x) ------
__global__ __launch_bounds__(256) void out_mfma(
    const __hip_bfloat16* __restrict__ agg, const short* __restrict__ Wpb,
    const float* __restrict__ bpf, const int* __restrict__ flag,
    void* __restrict__ dout)
{
    const bool f32 = (*flag != 0);
    const int wave = threadIdx.x >> 6, lane = threadIdx.x & 63;
    const int rb0 = blockIdx.x << 4;                 // 200 blocks x 16 rows = 3200
    const int m = lane & 15, qd = lane >> 4;

    const __hip_bfloat16* arow = agg + (size_t)(rb0 + m) * CDIM + qd * 8;
    short8 A[8];
    #pragma unroll
    for (int k = 0; k < 8; ++k)
        A[k] = *(const short8*)(arow + k * 32);

    #pragma unroll
    for (int p = 0; p < 2; ++p) {
        const int o0 = wave * 64 + p * 32;           // pair covers o0..o0+31
        floatx4 acc0 = {0.f, 0.f, 0.f, 0.f}, acc1 = {0.f, 0.f, 0.f, 0.f};
        #pragma unroll
        for (int k = 0; k < 8; ++k) {
            short8 b0 = *(const short8*)(Wpb + (size_t)(o0 + m) * CDIM + k * 32 + qd * 8);
            short8 b1 = *(const short8*)(Wpb + (size_t)(o0 + 16 + m) * CDIM + k * 32 + qd * 8);
            acc0 = __builtin_amdgcn_mfma_f32_16x16x32_bf16(A[k], b0, acc0, 0, 0, 0);
            acc1 = __builtin_amdgcn_mfma_f32_16x16x32_bf16(A[k], b1, acc1, 0, 0, 0);
        }
        const int oa = o0 + (lane & 15), ob = oa + 16;
        const float ba_ = bpf[oa];
        const float bb_ = bpf[ob];
        #pragma unroll
        for (int rg = 0; rg < 4; ++rg) {
            const int rb = rb0 + (lane >> 4) * 4 + rg;
            st_out(dout, (size_t)rb * CDIM + oa, acc0[rg] + ba_, f32);
            st_out(dout, (size_t)rb * CDIM + ob, acc1[rg] + bb_, f32);
        }
    }
}

extern "C" void kernel_launch(void* const* d_in, const int* in_sizes, int n_in,
                              void* d_out, int out_size, void* d_ws, size_t ws_size,
                              hipStream_t stream)
{
    const void* q   = d_in[0];
    const void* k   = d_in[1];
    const void* v   = d_in[2];
    const void* Wq  = d_in[3];
    const void* bq  = d_in[4];
    const void* Wk  = d_in[5];
    const void* bk  = d_in[6];
    const void* Wv  = d_in[7];
    const void* bv  = d_in[8];
    const void* rkw = d_in[9];
    const void* rkb = d_in[10];
    const void* rlv = d_in[11];
    const void* Wp  = d_in[12];
    const void* bp  = d_in[13];

    // ws layout (same offsets as before; Wqb/Wkb/Wvb/bqf/bkf/bvf slots unused):
    //   flag(64B) | relvT(115200B) | qs | ks | vs | agg (PROJ bf16 each)
    //   | [unused 3x131072] | Wpb(131072B) | rkwb(115200B) | rkbb(3600B)
    //   | [unused 3x1024] | bpf(1024B fp32)
    char* wsb = (char*)d_ws;
    int* flag = (int*)wsb;
    __hip_bfloat16* relvT = (__hip_bfloat16*)(wsb + 64);
    __hip_bfloat16* qs    = (__hip_bfloat16*)(wsb + 64 + 115200);
    __hip_bfloat16* ks    = qs + PROJ;
    __hip_bfloat16* vs    = ks + PROJ;
    __hip_bfloat16* agg   = vs + PROJ;
    __hip_bfloat16* Wpb   = (__hip_bfloat16*)(wsb + 6668864) + 3 * CDIM * CDIM;
    __hip_bfloat16* rkwb  = (__hip_bfloat16*)(wsb + 7193152);
    __hip_bfloat16* rkbb  = (__hip_bfloat16*)(wsb + 7308352);
    float* bpf = (float*)(wsb + 7311952) + 3 * CDIM;

    proj_fused<<<dim3(50, 2, 4), 512, 0, stream>>>(q, k, v, Wq, bq, Wk, bk, Wv, bv,
                                                   rkw, rkb, rlv, Wp, bp,
                                                   flag, relvT, rkwb, rkbb, Wpb, bpf,
                                                   qs, ks, vs);
    attn_mfma<<<dim3(120, 16), 256, 0, stream>>>(qs, ks, vs, (const short*)rkwb,
                                                 (const short*)rkbb, relvT, flag,
                                                 agg, d_out);
    out_mfma<<<200, 256, 0, stream>>>(agg, (const short*)Wpb, bpf, flag, d_out);
}

// Round 11
// 148.503 us; speedup vs baseline: 1.0463x; 1.0099x over previous
//
#include <hip/hip_runtime.h>
#include <hip/hip_bf16.h>

#define HW    1600
#define NB    2
#define NHEAD 8
#define HD    32
#define WS2   225
#define WDIM  40
#define CDIM  256
#define PROJ  819200                 // NB*NHEAD*HW*HD elements
#define RELSTR 248                   // LDS rel row stride (multiple of 8 shorts = 16B)
#define TSC   5.656854249492381f     // sqrt(32)

typedef __attribute__((ext_vector_type(8))) short short8;
typedef __attribute__((ext_vector_type(4))) short short4v;
typedef __attribute__((ext_vector_type(4))) float floatx4;

static __device__ __forceinline__ float bu2f(short u) {
    return __uint_as_float(((unsigned)(unsigned short)u) << 16);
}
static __device__ __forceinline__ short f2bu(float f) {
    __hip_bfloat16 h = __float2bfloat16(f);
    short s; __builtin_memcpy(&s, &h, 2); return s;
}
static __device__ __forceinline__ unsigned pk2(short a, short b) {
    return (unsigned)(unsigned short)a | ((unsigned)(unsigned short)b << 16);
}
static __device__ __forceinline__ float ldf(const void* p, size_t i, bool f32) {
    return f32 ? ((const float*)p)[i] : __bfloat162float(((const __hip_bfloat16*)p)[i]);
}
static __device__ __forceinline__ void st_out(void* p, size_t i, float v, bool f32) {
    if (f32) ((float*)p)[i] = v;
    else     ((__hip_bfloat16*)p)[i] = __float2bfloat16(v);
}

// ---------------- Kernel 1: prep = dtype detect + all weight conversions ----------
__global__ __launch_bounds__(256) void prep_kernel(
    const void* __restrict__ q, const void* __restrict__ relv,
    const void* __restrict__ Wq, const void* __restrict__ Wk,
    const void* __restrict__ Wv, const void* __restrict__ Wp,
    const void* __restrict__ bq, const void* __restrict__ bk,
    const void* __restrict__ bv, const void* __restrict__ bp,
    const void* __restrict__ rkw, const void* __restrict__ rkb,
    int* __restrict__ flag, __hip_bfloat16* __restrict__ relvT,
    __hip_bfloat16* __restrict__ Wqb, __hip_bfloat16* __restrict__ Wkb,
    __hip_bfloat16* __restrict__ Wvb, __hip_bfloat16* __restrict__ Wpb,
    float* __restrict__ bqf, float* __restrict__ bkf,
    float* __restrict__ bvf, float* __restrict__ bpf,
    __hip_bfloat16* __restrict__ rkwb, __hip_bfloat16* __restrict__ rkbb)
{
    __shared__ int sbad;
    if (threadIdx.x == 0) sbad = 0;
    __syncthreads();
    int bad = 0;
    const __hip_bfloat16* qb = (const __hip_bfloat16*)q;
    for (int i = threadIdx.x; i < 4096; i += 256) {
        float v = __bfloat162float(qb[i]);
        if (!(v > -1e6f && v < 1e6f)) bad = 1;   // fp32-misread garbage / NaN
    }
    if (bad) sbad = 1;
    __syncthreads();
    const bool f32 = (sbad != 0);
    if (blockIdx.x == 0 && threadIdx.x == 0) *flag = sbad;

    const int gid = blockIdx.x * 256 + threadIdx.x;
    const int gsz = gridDim.x * 256;

    // relvT: [h][w][d] transpose of relv [h][d][w]
    for (int e = gid; e < NHEAD * WS2 * HD; e += gsz) {
        const int h = e / (WS2 * HD), idx = e - h * (WS2 * HD);
        const int w = idx >> 5, d = idx & 31;
        relvT[e] = __float2bfloat16(ldf(relv, ((size_t)h * HD + d) * WS2 + w, f32));
    }
    for (int e = gid; e < CDIM * CDIM; e += gsz) {
        Wqb[e] = __float2bfloat16(ldf(Wq, e, f32));
        Wkb[e] = __float2bfloat16(ldf(Wk, e, f32));
        Wvb[e] = __float2bfloat16(ldf(Wv, e, f32));
        Wpb[e] = __float2bfloat16(ldf(Wp, e, f32));
    }
    for (int e = gid; e < CDIM; e += gsz) {
        bqf[e] = ldf(bq, e, f32); bkf[e] = ldf(bk, e, f32);
        bvf[e] = ldf(bv, e, f32); bpf[e] = ldf(bp, e, f32);
    }
    for (int e = gid; e < NHEAD * WS2 * HD; e += gsz)
        rkwb[e] = __float2bfloat16(ldf(rkw, e, f32));
    for (int e = gid; e < NHEAD * WS2; e += gsz)
        rkbb[e] = __float2bfloat16(ldf(rkb, e, f32));
}

// ---------------- Kernel 2: fused transpose + projection GEMM (q,k,v) -------------
// 512 threads / 8 waves per block: staging split across thread-halves,
// each wave computes 2 o-tile-groups.
__global__ __launch_bounds__(512) void proj_fused(
    const void* __restrict__ xq, const void* __restrict__ xk, const void* __restrict__ xv,
    const __hip_bfloat16* __restrict__ Wqb, const float* __restrict__ bqf,
    const __hip_bfloat16* __restrict__ Wkb, const float* __restrict__ bkf,
    const __hip_bfloat16* __restrict__ Wvb, const float* __restrict__ bvf,
    const int* __restrict__ flag,
    __hip_bfloat16* __restrict__ qs, __hip_bfloat16* __restrict__ ks,
    __hip_bfloat16* __restrict__ vs)
{
    __shared__ short xt[32][264];
    const bool f32 = (*flag != 0);
    const int tid = threadIdx.x;
    const int m0 = blockIdx.x * 32;
    const int n  = blockIdx.y;
    const int t  = blockIdx.z;
    const void* x; const short* W; const float* bias; __hip_bfloat16* dst; float scale;
    if (t == 0)      { x = xq; W = (const short*)Wqb; bias = bqf; dst = qs; scale = 0.17677669529663687f; }
    else if (t == 1) { x = xk; W = (const short*)Wkb; bias = bkf; dst = ks; scale = 1.f; }
    else             { x = xv; W = (const short*)Wvb; bias = bvf; dst = vs; scale = 1.f; }

    {
        const int c  = tid & 255;
        const int gh = tid >> 8;                    // which 16-row half of the tile
        const size_t xb = ((size_t)n * CDIM + c) * HW + m0 + gh * 16;
        if (f32) {
            const float* xr = (const float*)x + xb;
            #pragma unroll
            for (int g = 0; g < 4; ++g) {
                float4 f = *(const float4*)(xr + g * 4);
                xt[gh*16 + g*4+0][c] = f2bu(f.x); xt[gh*16 + g*4+1][c] = f2bu(f.y);
                xt[gh*16 + g*4+2][c] = f2bu(f.z); xt[gh*16 + g*4+3][c] = f2bu(f.w);
            }
        } else {
            const __hip_bfloat16* xr = (const __hip_bfloat16*)x + xb;
            short8 s0 = *(const short8*)(xr);
            short8 s1 = *(const short8*)(xr + 8);
            #pragma unroll
            for (int u = 0; u < 8; ++u) {
                xt[gh*16 + u][c]     = s0[u];
                xt[gh*16 + 8 + u][c] = s1[u];
            }
        }
    }
    __syncthreads();

    const int wave = tid >> 6, lane = tid & 63;     // wave 0..7
    const int m = lane & 15, qd = lane >> 4;

    short8 A[2][8];
    #pragma unroll
    for (int mt = 0; mt < 2; ++mt)
        #pragma unroll
        for (int k = 0; k < 8; ++k)
            A[mt][k] = *(const short8*)(&xt[mt*16 + m][k*32 + qd*8]);

    #pragma unroll
    for (int og = 0; og < 2; ++og) {
        const int o0 = (wave * 2 + og) * 16;        // 8 waves x 2 = 16 o-tiles
        short8 B[8];
        #pragma unroll
        for (int k = 0; k < 8; ++k)
            B[k] = *(const short8*)(W + (size_t)(o0 + m) * CDIM + k*32 + qd*8);
        floatx4 acc0 = {0,0,0,0}, acc1 = {0,0,0,0};
        #pragma unroll
        for (int k = 0; k < 8; ++k) {
            acc0 = __builtin_amdgcn_mfma_f32_16x16x32_bf16(A[0][k], B[k], acc0, 0, 0, 0);
            acc1 = __builtin_amdgcn_mfma_f32_16x16x32_bf16(A[1][k], B[k], acc1, 0, 0, 0);
        }
        const int o = o0 + (lane & 15), h = o >> 5, d = o & 31;
        const float bv_ = bias[o];
        #pragma unroll
        for (int rg = 0; rg < 4; ++rg) {
            const int p = m0 + (lane >> 4) * 4 + rg;
            dst[((size_t)(n*NHEAD + h)*HW + p)*HD + d]      = __float2bfloat16((acc0[rg] + bv_) * scale);
            dst[((size_t)(n*NHEAD + h)*HW + p + 16)*HD + d] = __float2bfloat16((acc1[rg] + bv_) * scale);
        }
    }
}

// ---------------- Kernel 3: full-MFMA fused local attention (rel in-kernel) -------
// Verified-best structure (146.0 us): QK operand-swapped, 31.75 KB LDS ->
// 5 blocks/CU, chunked V^T staging, coalesced attn_out copy phase.
// Session-measured dead ends (all reverted): direct dout store +10us (loses
// coalescing), setprio +3us, T14 reg-preload +9us (VGPR pressure),
// prep-fusion +4us (serialized conversions in proj critical path).
// LDS map:
//   sP  [16][488] u16 : kk-space P                         (15,616 B)  @0
//   R2: sRel [16][248] -> sPw [16][264] u16                ( 8,448 B)  @15,616
//   R1: sMax/sSum f32[64] -> V^T/Rv^T [16][264] u16 -> sOh f32[1024]
//                                                          ( 8,448 B)  @24,064
#define SP_OFF    0
#define R2_OFF    15616
#define R1_OFF    24064
#define SMAX_OFF  24064
#define SSUM_OFF  24320
#define SMEM_SZ   32512

__global__ __launch_bounds__(256, 5) void attn_mfma(
    const __hip_bfloat16* __restrict__ qs, const __hip_bfloat16* __restrict__ ks,
    const __hip_bfloat16* __restrict__ vs,
    const short* __restrict__ rkwb, const short* __restrict__ rkbb,
    const __hip_bfloat16* __restrict__ relvT,   // [h][w][d]
    const int* __restrict__ flag,
    __hip_bfloat16* __restrict__ agg,           // [hw, n, 256]
    void* __restrict__ dout)
{
    __shared__ __align__(16) char smem[SMEM_SZ];
    short* sP   = (short*)(smem + SP_OFF);
    short* sRel = (short*)(smem + R2_OFF);   // alias: dead before sPw writes
    short* sPw  = (short*)(smem + R2_OFF);
    short* sB   = (short*)(smem + R1_OFF);   // V^T chunks / Rv^T
    float* sOh  = (float*)(smem + R1_OFF);   // O partials (after MFMA reads)
    float* sMax = (float*)(smem + SMAX_OFF); // alias into R1 (dead before sB writes)
    float* sSum = (float*)(smem + SSUM_OFF);

    const bool f32 = (*flag != 0);
    const int tid = threadIdx.x;
    const int wave = tid >> 6, lane = tid & 63;
    const int m = lane & 15, quad = lane >> 4;
    const int y = blockIdx.x / 3, tile3 = blockIdx.x % 3;
    const int x0 = (tile3 == 0) ? 0 : (tile3 == 1) ? 16 : 24;
    const int wlo = (tile3 == 2) ? 8 : 0;
    const int nh_ = blockIdx.y;
    const int h = nh_ & 7, n = nh_ >> 3;
    const size_t qb = (size_t)nh_ * HW;
    const size_t qrow0 = qb + (size_t)y * WDIM + x0;

    const short8 afrag = *(const short8*)((const short*)qs + (qrow0 + m) * HD + quad * 8);

    // ---- rel[qm][w] = T*(qs . rkw) + rkb via 15 MFMAs (w-tiles split across waves) ----
    for (int wt = wave; wt < 15; wt += 4) {
        const int w0 = wt * 16;
        const int wl = min(w0 + m, WS2 - 1);
        const short8 B = *(const short8*)(rkwb + ((size_t)h * WS2 + wl) * HD + quad * 8);
        floatx4 acc = {0.f, 0.f, 0.f, 0.f};
        acc = __builtin_amdgcn_mfma_f32_16x16x32_bf16(afrag, B, acc, 0, 0, 0);
        const int wcol = w0 + m;                  // D: col=lane&15, row=quad*4+rg
        if (wcol < WS2) {
            const float rb_ = bu2f(rkbb[(size_t)h * WS2 + wcol]);
            #pragma unroll
            for (int rg = 0; rg < 4; ++rg)
                sRel[(quad * 4 + rg) * RELSTR + wcol] = f2bu(acc[rg] * TSC + rb_);
        }
    }
    __syncthreads();

    // ---- S^T = K.Q^T + rel : D[row=key][col=query], lane owns query m ----
    float L[8][4];
    #pragma unroll
    for (int j = 0; j < 8; ++j)
        #pragma unroll
        for (int rg = 0; rg < 4; ++rg) L[j][rg] = -1e30f;

    #pragma unroll
    for (int j = 0; j < 8; ++j) {
        const int t = wave + 4 * j;
        if (t < 30) {
            const int r = t >> 1, c0_ = (t & 1) << 4;
            const int cc = c0_ + m;                 // key row this lane LOADS
            const int ky = y + r - 7, kxl = x0 - 7 + cc;
            const int gky = min(max(ky, 0), WDIM - 1), gkx = min(max(kxl, 0), WDIM - 1);
            const short8 kfrag = *(const short8*)((const short*)ks + (qb + (size_t)gky * WDIM + gkx) * HD + quad * 8);
            floatx4 s4 = {0.f, 0.f, 0.f, 0.f};
            s4 = __builtin_amdgcn_mfma_f32_16x16x32_bf16(kfrag, afrag, s4, 0, 0, 0);
            const bool kyok = (unsigned)ky < (unsigned)WDIM;
            #pragma unroll
            for (int rg = 0; rg < 4; ++rg) {
                const int kkc = c0_ + quad * 4 + rg;   // D row = key col 0..31
                const int kx = x0 - 7 + kkc;
                const int dx7 = kkc - m;
                if (kyok && (unsigned)kx < (unsigned)WDIM && (unsigned)dx7 < 15u)
                    L[j][rg] = s4[rg] + bu2f(sRel[m * RELSTR + r * 15 + dx7]);
            }
        }
    }

    // ---- block softmax: lane owns one query; in-lane reduce + 2 shfl + 4-wave LDS ----
    float mx = L[0][0];
    #pragma unroll
    for (int j = 0; j < 8; ++j)
        #pragma unroll
        for (int rg = 0; rg < 4; ++rg) mx = fmaxf(mx, L[j][rg]);
    mx = fmaxf(mx, __shfl_xor(mx, 16));
    mx = fmaxf(mx, __shfl_xor(mx, 32));
    if (lane < 16) sMax[lane * 4 + wave] = mx;
    __syncthreads();
    const float4 vM = *(const float4*)&sMax[m * 4];
    const float M = fmaxf(fmaxf(vM.x, vM.y), fmaxf(vM.z, vM.w));
    float sm = 0.f;
    #pragma unroll
    for (int j = 0; j < 8; ++j)
        #pragma unroll
        for (int rg = 0; rg < 4; ++rg) { L[j][rg] = __expf(L[j][rg] - M); sm += L[j][rg]; }
    sm += __shfl_xor(sm, 16);
    sm += __shfl_xor(sm, 32);
    if (lane < 16) sSum[lane * 4 + wave] = sm;
    __syncthreads();
    const float4 vS = *(const float4*)&sSum[m * 4];
    const float inv = 1.f / (vS.x + vS.y + vS.z + vS.w);

    // ---- zero sPw gap/pad cols: r*16+15 (r=0..14) and 240..263 (39 cols/row) ----
    for (int e = tid; e < 16 * 39; e += 256) {
        const int row = e / 39, idx = e - row * 39;
        const int c = (idx < 15) ? idx * 16 + 15 : 240 + (idx - 15);
        sPw[row * 264 + c] = 0;
    }

    // ---- write P: sP packed 8B (4 consecutive kk); sPw window layout r*16+dx7 ----
    #pragma unroll
    for (int j = 0; j < 8; ++j) {
        const int t = wave + 4 * j;
        if (t < 30) {
            const int r = t >> 1, c0_ = (t & 1) << 4;
            const int kb = c0_ + quad * 4;
            short4v pk;
            #pragma unroll
            for (int rg = 0; rg < 4; ++rg) pk[rg] = f2bu(L[j][rg] * inv);  // exact 0 when invalid
            *(short4v*)(sP + m * 488 + r * 32 + kb) = pk;
            #pragma unroll
            for (int rg = 0; rg < 4; ++rg) {
                const int dx7 = kb + rg - m;
                if ((unsigned)dx7 < 15u) sPw[m * 264 + r * 16 + dx7] = pk[rg];
            }
        }
    }
    __syncthreads();

    // ---- coalesced attn_out copy from window-space P (col w -> kcol r*16+dx7) ----
    #pragma unroll
    for (int rr = 0; rr < 4; ++rr) {
        const int qm = wave * 4 + rr;
        if (qm >= wlo) {
            const size_t obase = (size_t)PROJ + (qrow0 + qm) * WS2;
            #pragma unroll
            for (int c = 0; c < 4; ++c) {
                const int col = lane + 64 * c;
                if (col < WS2) {
                    const int rq = col / 15, dxq = col - rq * 15;
                    st_out(dout, obase + col, bu2f(sPw[qm * 264 + rq * 16 + dxq]), f32);
                }
            }
        }
    }

    // ---- PV + rel_v GEMMs, d in halves of 16; V^T staged in two kk-chunks ----
    for (int half = 0; half < 2; ++half) {
        __syncthreads();
        const int h16 = half << 4;
        {   // stage V^T chunk0: kk rows 0..7 (kk 0..255), 128 pair-items
            if (tid < 128) {
                unsigned* dstw = (unsigned*)sB;
                const int kk0 = 2 * tid;
                const int r = kk0 >> 5, c = kk0 & 31;
                const int gky = min(max(y + r - 7, 0), WDIM - 1);
                const int gkx0 = min(max(x0 - 7 + c, 0), WDIM - 1);
                const int gkx1 = min(max(x0 - 7 + c + 1, 0), WDIM - 1);
                const short* v0 = (const short*)vs + (qb + (size_t)gky * WDIM + gkx0) * HD + h16;
                const short* v1 = (const short*)vs + (qb + (size_t)gky * WDIM + gkx1) * HD + h16;
                const short8 a0 = *(const short8*)v0, b0 = *(const short8*)v1;
                const short8 a1 = *(const short8*)(v0 + 8), b1 = *(const short8*)(v1 + 8);
                #pragma unroll
                for (int dd = 0; dd < 8; ++dd) dstw[dd * 132 + tid] = pk2(a0[dd], b0[dd]);
                #pragma unroll
                for (int dd = 0; dd < 8; ++dd) dstw[(dd + 8) * 132 + tid] = pk2(a1[dd], b1[dd]);
            }
        }
        __syncthreads();
        floatx4 acc = {0.f, 0.f, 0.f, 0.f};
        for (int u = wave; u < 8; u += 4) {          // u = wave, wave+4
            const short8 Af = *(const short8*)(sP + m * 488 + u * 32 + quad * 8);
            const short8 Bf = *(const short8*)(sB + m * 264 + u * 32 + quad * 8);
            acc = __builtin_amdgcn_mfma_f32_16x16x32_bf16(Af, Bf, acc, 0, 0, 0);
        }
        __syncthreads();
        {   // stage V^T chunk1: kk rows 8..14 (kk 256..479), 112 pair-items
            if (tid < 112) {
                unsigned* dstw = (unsigned*)sB;
                const int kk0 = 256 + 2 * tid;
                const int r = kk0 >> 5, c = kk0 & 31;
                const int gky = min(max(y + r - 7, 0), WDIM - 1);
                const int gkx0 = min(max(x0 - 7 + c, 0), WDIM - 1);
                const int gkx1 = min(max(x0 - 7 + c + 1, 0), WDIM - 1);
                const short* v0 = (const short*)vs + (qb + (size_t)gky * WDIM + gkx0) * HD + h16;
                const short* v1 = (const short*)vs + (qb + (size_t)gky * WDIM + gkx1) * HD + h16;
                const short8 a0 = *(const short8*)v0, b0 = *(const short8*)v1;
                const short8 a1 = *(const short8*)(v0 + 8), b1 = *(const short8*)(v1 + 8);
                #pragma unroll
                for (int dd = 0; dd < 8; ++dd) dstw[dd * 132 + tid] = pk2(a0[dd], b0[dd]);
                #pragma unroll
                for (int dd = 0; dd < 8; ++dd) dstw[(dd + 8) * 132 + tid] = pk2(a1[dd], b1[dd]);
            }
        }
        __syncthreads();
        for (int u = 8 + wave; u < 15; u += 4) {     // u = 8+wave, 12+wave
            const short8 Af = *(const short8*)(sP + m * 488 + u * 32 + quad * 8);
            const short8 Bf = *(const short8*)(sB + m * 264 + (u - 8) * 32 + quad * 8);
            acc = __builtin_amdgcn_mfma_f32_16x16x32_bf16(Af, Bf, acc, 0, 0, 0);
        }
        __syncthreads();
        {   // stage Rv^T rows [d-half][kcol], stride 264 shorts; kcol = r*16+dx7,
            // gap cols (dx7==15) and kcol>=240 zero
            unsigned* dstw = (unsigned*)sB;
            for (int p = tid; p < 132; p += 256) {
                short8 a0 = {0,0,0,0,0,0,0,0}, a1 = a0, b0 = a0, b1 = a0;
                if (p < 120) {
                    const int kcol0 = 2 * p;
                    const int r = kcol0 >> 4, dx = kcol0 & 15;   // dx even <= 14
                    const int w0 = r * 15 + dx;                   // <= 224
                    const short* rp = (const short*)relvT + ((size_t)h * WS2 + w0) * HD + h16;
                    a0 = *(const short8*)rp; a1 = *(const short8*)(rp + 8);
                    if (dx < 14) {   // kcol0+1 in-window; dx==14 -> gap col, stays 0
                        const short* rq = (const short*)relvT + ((size_t)h * WS2 + w0 + 1) * HD + h16;
                        b0 = *(const short8*)rq; b1 = *(const short8*)(rq + 8);
                    }
                }
                #pragma unroll
                for (int dd = 0; dd < 8; ++dd) dstw[dd * 132 + p] = pk2(a0[dd], b0[dd]);
                #pragma unroll
                for (int dd = 0; dd < 8; ++dd) dstw[(dd + 8) * 132 + p] = pk2(a1[dd], b1[dd]);
            }
        }
        __syncthreads();
        for (int u = wave; u < 8; u += 4) {
            const short8 Af = *(const short8*)(sPw + m * 264 + u * 32 + quad * 8);
            const short8 Bf = *(const short8*)(sB + m * 264 + u * 32 + quad * 8);
            acc = __builtin_amdgcn_mfma_f32_16x16x32_bf16(Af, Bf, acc, 0, 0, 0);
        }
        __syncthreads();
        #pragma unroll
        for (int rg = 0; rg < 4; ++rg)
            sOh[wave * 256 + (quad * 4 + rg) * 16 + m] = acc[rg];
        __syncthreads();
        {
            const int qq = tid >> 4, dd = tid & 15;
            const float s = sOh[tid] + sOh[256 + tid] + sOh[512 + tid] + sOh[768 + tid];
            if (qq >= wlo) {
                const size_t i = (size_t)y * WDIM + x0 + qq;
                agg[(i * NB + n) * CDIM + h * HD + h16 + dd] = __float2bfloat16(s);
            }
        }
    }
}

// ---------------- Kernel 4: output projection via MFMA (A-frags reused 8x) ------
__global__ __launch_bounds__(256) void out_mfma(
    const __hip_bfloat16* __restrict__ agg, const short* __restrict__ Wpb,
    const float* __restrict__ bpf, const int* __restrict__ flag,
    void* __restrict__ dout)
{
    const bool f32 = (*flag != 0);
    const int wave = threadIdx.x >> 6, lane = threadIdx.x & 63;
    const int rb0 = blockIdx.x << 4;                 // 200 blocks x 16 rows = 3200
    const int m = lane & 15, qd = lane >> 4;

    const __hip_bfloat16* arow = agg + (size_t)(rb0 + m) * CDIM + qd * 8;
    short8 A[8];
    #pragma unroll
    for (int k = 0; k < 8; ++k)
        A[k] = *(const short8*)(arow + k * 32);

    #pragma unroll
    for (int p = 0; p < 2; ++p) {
        const int o0 = wave * 64 + p * 32;           // pair covers o0..o0+31
        floatx4 acc0 = {0.f, 0.f, 0.f, 0.f}, acc1 = {0.f, 0.f, 0.f, 0.f};
        #pragma unroll
        for (int k = 0; k < 8; ++k) {
            short8 b0 = *(const short8*)(Wpb + (size_t)(o0 + m) * CDIM + k * 32 + qd * 8);
            short8 b1 = *(const short8*)(Wpb + (size_t)(o0 + 16 + m) * CDIM + k * 32 + qd * 8);
            acc0 = __builtin_amdgcn_mfma_f32_16x16x32_bf16(A[k], b0, acc0, 0, 0, 0);
            acc1 = __builtin_amdgcn_mfma_f32_16x16x32_bf16(A[k], b1, acc1, 0, 0, 0);
        }
        const int oa = o0 + (lane & 15), ob = oa + 16;
        const float ba_ = bpf[oa];
        const float bb_ = bpf[ob];
        #pragma unroll
        for (int rg = 0; rg < 4; ++rg) {
            const int rb = rb0 + (lane >> 4) * 4 + rg;
            st_out(dout, (size_t)rb * CDIM + oa, acc0[rg] + ba_, f32);
            st_out(dout, (size_t)rb * CDIM + ob, acc1[rg] + bb_, f32);
        }
    }
}

extern "C" void kernel_launch(void* const* d_in, const int* in_sizes, int n_in,
                              void* d_out, int out_size, void* d_ws, size_t ws_size,
                              hipStream_t stream)
{
    const void* q   = d_in[0];
    const void* k   = d_in[1];
    const void* v   = d_in[2];
    const void* Wq  = d_in[3];
    const void* bq  = d_in[4];
    const void* Wk  = d_in[5];
    const void* bk  = d_in[6];
    const void* Wv  = d_in[7];
    const void* bv  = d_in[8];
    const void* rkw = d_in[9];
    const void* rkb = d_in[10];
    const void* rlv = d_in[11];
    const void* Wp  = d_in[12];
    const void* bp  = d_in[13];

    // ws layout (7.32 MB):
    //   flag(64B) | relvT(115200B) | qs | ks | vs | agg (PROJ bf16 each)
    //   | Wqb|Wkb|Wvb|Wpb (131072B each) | rkwb(115200B) | rkbb(3600B)
    //   | bqf|bkf|bvf|bpf (1024B each, fp32)
    char* wsb = (char*)d_ws;
    int* flag = (int*)wsb;
    __hip_bfloat16* relvT = (__hip_bfloat16*)(wsb + 64);
    __hip_bfloat16* qs    = (__hip_bfloat16*)(wsb + 64 + 115200);
    __hip_bfloat16* ks    = qs + PROJ;
    __hip_bfloat16* vs    = ks + PROJ;
    __hip_bfloat16* agg   = vs + PROJ;
    __hip_bfloat16* Wqb   = (__hip_bfloat16*)(wsb + 6668864);
    __hip_bfloat16* Wkb   = Wqb + CDIM * CDIM;
    __hip_bfloat16* Wvb   = Wkb + CDIM * CDIM;
    __hip_bfloat16* Wpb   = Wvb + CDIM * CDIM;
    __hip_bfloat16* rkwb  = (__hip_bfloat16*)(wsb + 7193152);
    __hip_bfloat16* rkbb  = (__hip_bfloat16*)(wsb + 7308352);
    float* bqf = (float*)(wsb + 7311952);
    float* bkf = bqf + CDIM;
    float* bvf = bkf + CDIM;
    float* bpf = bvf + CDIM;

    prep_kernel<<<128, 256, 0, stream>>>(q, rlv, Wq, Wk, Wv, Wp, bq, bk, bv, bp,
                                         rkw, rkb, flag, relvT,
                                         Wqb, Wkb, Wvb, Wpb, bqf, bkf, bvf, bpf,
                                         rkwb, rkbb);
    proj_fused<<<dim3(50, 2, 3), 512, 0, stream>>>(q, k, v, Wqb, bqf, Wkb, bkf,
                                                   Wvb, bvf, flag, qs, ks, vs);
    attn_mfma<<<dim3(120, 16), 256, 0, stream>>>(qs, ks, vs, (const short*)rkwb,
                                                 (const short*)rkbb, relvT, flag,
                                                 agg, d_out);
    out_mfma<<<200, 256, 0, stream>>>(agg, (const short*)Wpb, bpf, flag, d_out);
}

// Round 12
// 145.691 us; speedup vs baseline: 1.0665x; 1.0193x over previous
//
#include <hip/hip_runtime.h>
#include <hip/hip_bf16.h>

#define HW    1600
#define NB    2
#define NHEAD 8
#define HD    32
#define WS2   225
#define WDIM  40
#define CDIM  256
#define PROJ  819200                 // NB*NHEAD*HW*HD elements
#define RELSTR 248                   // LDS rel row stride (multiple of 8 shorts = 16B)
#define TSC   5.656854249492381f     // sqrt(32)

typedef __attribute__((ext_vector_type(8))) short short8;
typedef __attribute__((ext_vector_type(4))) short short4v;
typedef __attribute__((ext_vector_type(4))) float floatx4;

static __device__ __forceinline__ float bu2f(short u) {
    return __uint_as_float(((unsigned)(unsigned short)u) << 16);
}
static __device__ __forceinline__ short f2bu(float f) {
    __hip_bfloat16 h = __float2bfloat16(f);
    short s; __builtin_memcpy(&s, &h, 2); return s;
}
static __device__ __forceinline__ unsigned pk2(short a, short b) {
    return (unsigned)(unsigned short)a | ((unsigned)(unsigned short)b << 16);
}
static __device__ __forceinline__ float ldf(const void* p, size_t i, bool f32) {
    return f32 ? ((const float*)p)[i] : __bfloat162float(((const __hip_bfloat16*)p)[i]);
}
static __device__ __forceinline__ void st_out(void* p, size_t i, float v, bool f32) {
    if (f32) ((float*)p)[i] = v;
    else     ((__hip_bfloat16*)p)[i] = __float2bfloat16(v);
}

// ---------------- Kernel 1: prep = dtype detect + all weight conversions ----------
__global__ __launch_bounds__(256) void prep_kernel(
    const void* __restrict__ q, const void* __restrict__ relv,
    const void* __restrict__ Wq, const void* __restrict__ Wk,
    const void* __restrict__ Wv, const void* __restrict__ Wp,
    const void* __restrict__ bq, const void* __restrict__ bk,
    const void* __restrict__ bv, const void* __restrict__ bp,
    const void* __restrict__ rkw, const void* __restrict__ rkb,
    int* __restrict__ flag, __hip_bfloat16* __restrict__ relvT,
    __hip_bfloat16* __restrict__ Wqb, __hip_bfloat16* __restrict__ Wkb,
    __hip_bfloat16* __restrict__ Wvb, __hip_bfloat16* __restrict__ Wpb,
    float* __restrict__ bqf, float* __restrict__ bkf,
    float* __restrict__ bvf, float* __restrict__ bpf,
    __hip_bfloat16* __restrict__ rkwb, __hip_bfloat16* __restrict__ rkbb)
{
    __shared__ int sbad;
    if (threadIdx.x == 0) sbad = 0;
    __syncthreads();
    int bad = 0;
    const __hip_bfloat16* qb = (const __hip_bfloat16*)q;
    for (int i = threadIdx.x; i < 4096; i += 256) {
        float v = __bfloat162float(qb[i]);
        if (!(v > -1e6f && v < 1e6f)) bad = 1;   // fp32-misread garbage / NaN
    }
    if (bad) sbad = 1;
    __syncthreads();
    const bool f32 = (sbad != 0);
    if (blockIdx.x == 0 && threadIdx.x == 0) *flag = sbad;

    const int gid = blockIdx.x * 256 + threadIdx.x;
    const int gsz = gridDim.x * 256;

    // relvT: [h][w][d] transpose of relv [h][d][w]
    for (int e = gid; e < NHEAD * WS2 * HD; e += gsz) {
        const int h = e / (WS2 * HD), idx = e - h * (WS2 * HD);
        const int w = idx >> 5, d = idx & 31;
        relvT[e] = __float2bfloat16(ldf(relv, ((size_t)h * HD + d) * WS2 + w, f32));
    }
    for (int e = gid; e < CDIM * CDIM; e += gsz) {
        Wqb[e] = __float2bfloat16(ldf(Wq, e, f32));
        Wkb[e] = __float2bfloat16(ldf(Wk, e, f32));
        Wvb[e] = __float2bfloat16(ldf(Wv, e, f32));
        Wpb[e] = __float2bfloat16(ldf(Wp, e, f32));
    }
    for (int e = gid; e < CDIM; e += gsz) {
        bqf[e] = ldf(bq, e, f32); bkf[e] = ldf(bk, e, f32);
        bvf[e] = ldf(bv, e, f32); bpf[e] = ldf(bp, e, f32);
    }
    for (int e = gid; e < NHEAD * WS2 * HD; e += gsz)
        rkwb[e] = __float2bfloat16(ldf(rkw, e, f32));
    for (int e = gid; e < NHEAD * WS2; e += gsz)
        rkbb[e] = __float2bfloat16(ldf(rkb, e, f32));
}

// ---------------- Kernel 2: fused transpose + projection GEMM (q,k,v) -------------
// 512 threads / 8 waves per block: staging split across thread-halves,
// each wave computes 2 o-tile-groups.
__global__ __launch_bounds__(512) void proj_fused(
    const void* __restrict__ xq, const void* __restrict__ xk, const void* __restrict__ xv,
    const __hip_bfloat16* __restrict__ Wqb, const float* __restrict__ bqf,
    const __hip_bfloat16* __restrict__ Wkb, const float* __restrict__ bkf,
    const __hip_bfloat16* __restrict__ Wvb, const float* __restrict__ bvf,
    const int* __restrict__ flag,
    __hip_bfloat16* __restrict__ qs, __hip_bfloat16* __restrict__ ks,
    __hip_bfloat16* __restrict__ vs)
{
    __shared__ short xt[32][264];
    const bool f32 = (*flag != 0);
    const int tid = threadIdx.x;
    const int m0 = blockIdx.x * 32;
    const int n  = blockIdx.y;
    const int t  = blockIdx.z;
    const void* x; const short* W; const float* bias; __hip_bfloat16* dst; float scale;
    if (t == 0)      { x = xq; W = (const short*)Wqb; bias = bqf; dst = qs; scale = 0.17677669529663687f; }
    else if (t == 1) { x = xk; W = (const short*)Wkb; bias = bkf; dst = ks; scale = 1.f; }
    else             { x = xv; W = (const short*)Wvb; bias = bvf; dst = vs; scale = 1.f; }

    {
        const int c  = tid & 255;
        const int gh = tid >> 8;                    // which 16-row half of the tile
        const size_t xb = ((size_t)n * CDIM + c) * HW + m0 + gh * 16;
        if (f32) {
            const float* xr = (const float*)x + xb;
            #pragma unroll
            for (int g = 0; g < 4; ++g) {
                float4 f = *(const float4*)(xr + g * 4);
                xt[gh*16 + g*4+0][c] = f2bu(f.x); xt[gh*16 + g*4+1][c] = f2bu(f.y);
                xt[gh*16 + g*4+2][c] = f2bu(f.z); xt[gh*16 + g*4+3][c] = f2bu(f.w);
            }
        } else {
            const __hip_bfloat16* xr = (const __hip_bfloat16*)x + xb;
            short8 s0 = *(const short8*)(xr);
            short8 s1 = *(const short8*)(xr + 8);
            #pragma unroll
            for (int u = 0; u < 8; ++u) {
                xt[gh*16 + u][c]     = s0[u];
                xt[gh*16 + 8 + u][c] = s1[u];
            }
        }
    }
    __syncthreads();

    const int wave = tid >> 6, lane = tid & 63;     // wave 0..7
    const int m = lane & 15, qd = lane >> 4;

    short8 A[2][8];
    #pragma unroll
    for (int mt = 0; mt < 2; ++mt)
        #pragma unroll
        for (int k = 0; k < 8; ++k)
            A[mt][k] = *(const short8*)(&xt[mt*16 + m][k*32 + qd*8]);

    #pragma unroll
    for (int og = 0; og < 2; ++og) {
        const int o0 = (wave * 2 + og) * 16;        // 8 waves x 2 = 16 o-tiles
        short8 B[8];
        #pragma unroll
        for (int k = 0; k < 8; ++k)
            B[k] = *(const short8*)(W + (size_t)(o0 + m) * CDIM + k*32 + qd*8);
        floatx4 acc0 = {0,0,0,0}, acc1 = {0,0,0,0};
        #pragma unroll
        for (int k = 0; k < 8; ++k) {
            acc0 = __builtin_amdgcn_mfma_f32_16x16x32_bf16(A[0][k], B[k], acc0, 0, 0, 0);
            acc1 = __builtin_amdgcn_mfma_f32_16x16x32_bf16(A[1][k], B[k], acc1, 0, 0, 0);
        }
        const int o = o0 + (lane & 15), h = o >> 5, d = o & 31;
        const float bv_ = bias[o];
        #pragma unroll
        for (int rg = 0; rg < 4; ++rg) {
            const int p = m0 + (lane >> 4) * 4 + rg;
            dst[((size_t)(n*NHEAD + h)*HW + p)*HD + d]      = __float2bfloat16((acc0[rg] + bv_) * scale);
            dst[((size_t)(n*NHEAD + h)*HW + p + 16)*HD + d] = __float2bfloat16((acc1[rg] + bv_) * scale);
        }
    }
}

// ---------------- Kernel 3: full-MFMA fused local attention (rel in-kernel) -------
// Verified-best structure (146.0 us) + T1 XCD-aware bijective block swizzle:
// flat work id w = nh*120 + (y*3+tile3); executed as swz = (bid&7)*240+(bid>>3)
// (1920 = 8*240, bijective) so each XCD owns 2 heads -> K/V (408 KB) stays
// L2-resident per XCD instead of 8x cold HBM fetches (r8: FETCH 15MB vs ~5MB
// unique). Zero memory-behavior change beyond execution order.
// LDS map:
//   sP  [16][488] u16 : kk-space P                         (15,616 B)  @0
//   R2: sRel [16][248] -> sPw [16][264] u16                ( 8,448 B)  @15,616
//   R1: sMax/sSum f32[64] -> V^T/Rv^T [16][264] u16 -> sOh f32[1024]
//                                                          ( 8,448 B)  @24,064
#define SP_OFF    0
#define R2_OFF    15616
#define R1_OFF    24064
#define SMAX_OFF  24064
#define SSUM_OFF  24320
#define SMEM_SZ   32512

__global__ __launch_bounds__(256, 5) void attn_mfma(
    const __hip_bfloat16* __restrict__ qs, const __hip_bfloat16* __restrict__ ks,
    const __hip_bfloat16* __restrict__ vs,
    const short* __restrict__ rkwb, const short* __restrict__ rkbb,
    const __hip_bfloat16* __restrict__ relvT,   // [h][w][d]
    const int* __restrict__ flag,
    __hip_bfloat16* __restrict__ agg,           // [hw, n, 256]
    void* __restrict__ dout)
{
    __shared__ __align__(16) char smem[SMEM_SZ];
    short* sP   = (short*)(smem + SP_OFF);
    short* sRel = (short*)(smem + R2_OFF);   // alias: dead before sPw writes
    short* sPw  = (short*)(smem + R2_OFF);
    short* sB   = (short*)(smem + R1_OFF);   // V^T chunks / Rv^T
    float* sOh  = (float*)(smem + R1_OFF);   // O partials (after MFMA reads)
    float* sMax = (float*)(smem + SMAX_OFF); // alias into R1 (dead before sB writes)
    float* sSum = (float*)(smem + SSUM_OFF);

    const bool f32 = (*flag != 0);
    const int tid = threadIdx.x;
    const int wave = tid >> 6, lane = tid & 63;
    const int m = lane & 15, quad = lane >> 4;

    // T1: bijective XCD swizzle (1920 blocks = 8 XCDs x 240)
    const int bid = blockIdx.y * 120 + blockIdx.x;
    const int swz = (bid & 7) * 240 + (bid >> 3);
    const int nh_ = swz / 120;
    const int rem = swz - nh_ * 120;
    const int y = rem / 3, tile3 = rem % 3;

    const int x0 = (tile3 == 0) ? 0 : (tile3 == 1) ? 16 : 24;
    const int wlo = (tile3 == 2) ? 8 : 0;
    const int h = nh_ & 7, n = nh_ >> 3;
    const size_t qb = (size_t)nh_ * HW;
    const size_t qrow0 = qb + (size_t)y * WDIM + x0;

    const short8 afrag = *(const short8*)((const short*)qs + (qrow0 + m) * HD + quad * 8);

    // ---- rel[qm][w] = T*(qs . rkw) + rkb via 15 MFMAs (w-tiles split across waves) ----
    for (int wt = wave; wt < 15; wt += 4) {
        const int w0 = wt * 16;
        const int wl = min(w0 + m, WS2 - 1);
        const short8 B = *(const short8*)(rkwb + ((size_t)h * WS2 + wl) * HD + quad * 8);
        floatx4 acc = {0.f, 0.f, 0.f, 0.f};
        acc = __builtin_amdgcn_mfma_f32_16x16x32_bf16(afrag, B, acc, 0, 0, 0);
        const int wcol = w0 + m;                  // D: col=lane&15, row=quad*4+rg
        if (wcol < WS2) {
            const float rb_ = bu2f(rkbb[(size_t)h * WS2 + wcol]);
            #pragma unroll
            for (int rg = 0; rg < 4; ++rg)
                sRel[(quad * 4 + rg) * RELSTR + wcol] = f2bu(acc[rg] * TSC + rb_);
        }
    }
    __syncthreads();

    // ---- S^T = K.Q^T + rel : D[row=key][col=query], lane owns query m ----
    float L[8][4];
    #pragma unroll
    for (int j = 0; j < 8; ++j)
        #pragma unroll
        for (int rg = 0; rg < 4; ++rg) L[j][rg] = -1e30f;

    #pragma unroll
    for (int j = 0; j < 8; ++j) {
        const int t = wave + 4 * j;
        if (t < 30) {
            const int r = t >> 1, c0_ = (t & 1) << 4;
            const int cc = c0_ + m;                 // key row this lane LOADS
            const int ky = y + r - 7, kxl = x0 - 7 + cc;
            const int gky = min(max(ky, 0), WDIM - 1), gkx = min(max(kxl, 0), WDIM - 1);
            const short8 kfrag = *(const short8*)((const short*)ks + (qb + (size_t)gky * WDIM + gkx) * HD + quad * 8);
            floatx4 s4 = {0.f, 0.f, 0.f, 0.f};
            s4 = __builtin_amdgcn_mfma_f32_16x16x32_bf16(kfrag, afrag, s4, 0, 0, 0);
            const bool kyok = (unsigned)ky < (unsigned)WDIM;
            #pragma unroll
            for (int rg = 0; rg < 4; ++rg) {
                const int kkc = c0_ + quad * 4 + rg;   // D row = key col 0..31
                const int kx = x0 - 7 + kkc;
                const int dx7 = kkc - m;
                if (kyok && (unsigned)kx < (unsigned)WDIM && (unsigned)dx7 < 15u)
                    L[j][rg] = s4[rg] + bu2f(sRel[m * RELSTR + r * 15 + dx7]);
            }
        }
    }

    // ---- block softmax: lane owns one query; in-lane reduce + 2 shfl + 4-wave LDS ----
    float mx = L[0][0];
    #pragma unroll
    for (int j = 0; j < 8; ++j)
        #pragma unroll
        for (int rg = 0; rg < 4; ++rg) mx = fmaxf(mx, L[j][rg]);
    mx = fmaxf(mx, __shfl_xor(mx, 16));
    mx = fmaxf(mx, __shfl_xor(mx, 32));
    if (lane < 16) sMax[lane * 4 + wave] = mx;
    __syncthreads();
    const float4 vM = *(const float4*)&sMax[m * 4];
    const float M = fmaxf(fmaxf(vM.x, vM.y), fmaxf(vM.z, vM.w));
    float sm = 0.f;
    #pragma unroll
    for (int j = 0; j < 8; ++j)
        #pragma unroll
        for (int rg = 0; rg < 4; ++rg) { L[j][rg] = __expf(L[j][rg] - M); sm += L[j][rg]; }
    sm += __shfl_xor(sm, 16);
    sm += __shfl_xor(sm, 32);
    if (lane < 16) sSum[lane * 4 + wave] = sm;
    __syncthreads();
    const float4 vS = *(const float4*)&sSum[m * 4];
    const float inv = 1.f / (vS.x + vS.y + vS.z + vS.w);

    // ---- zero sPw gap/pad cols: r*16+15 (r=0..14) and 240..263 (39 cols/row) ----
    for (int e = tid; e < 16 * 39; e += 256) {
        const int row = e / 39, idx = e - row * 39;
        const int c = (idx < 15) ? idx * 16 + 15 : 240 + (idx - 15);
        sPw[row * 264 + c] = 0;
    }

    // ---- write P: sP packed 8B (4 consecutive kk); sPw window layout r*16+dx7 ----
    #pragma unroll
    for (int j = 0; j < 8; ++j) {
        const int t = wave + 4 * j;
        if (t < 30) {
            const int r = t >> 1, c0_ = (t & 1) << 4;
            const int kb = c0_ + quad * 4;
            short4v pk;
            #pragma unroll
            for (int rg = 0; rg < 4; ++rg) pk[rg] = f2bu(L[j][rg] * inv);  // exact 0 when invalid
            *(short4v*)(sP + m * 488 + r * 32 + kb) = pk;
            #pragma unroll
            for (int rg = 0; rg < 4; ++rg) {
                const int dx7 = kb + rg - m;
                if ((unsigned)dx7 < 15u) sPw[m * 264 + r * 16 + dx7] = pk[rg];
            }
        }
    }
    __syncthreads();

    // ---- coalesced attn_out copy from window-space P (col w -> kcol r*16+dx7) ----
    #pragma unroll
    for (int rr = 0; rr < 4; ++rr) {
        const int qm = wave * 4 + rr;
        if (qm >= wlo) {
            const size_t obase = (size_t)PROJ + (qrow0 + qm) * WS2;
            #pragma unroll
            for (int c = 0; c < 4; ++c) {
                const int col = lane + 64 * c;
                if (col < WS2) {
                    const int rq = col / 15, dxq = col - rq * 15;
                    st_out(dout, obase + col, bu2f(sPw[qm * 264 + rq * 16 + dxq]), f32);
                }
            }
        }
    }

    // ---- PV + rel_v GEMMs, d in halves of 16; V^T staged in two kk-chunks ----
    for (int half = 0; half < 2; ++half) {
        __syncthreads();
        const int h16 = half << 4;
        {   // stage V^T chunk0: kk rows 0..7 (kk 0..255), 128 pair-items
            if (tid < 128) {
                unsigned* dstw = (unsigned*)sB;
                const int kk0 = 2 * tid;
                const int r = kk0 >> 5, c = kk0 & 31;
                const int gky = min(max(y + r - 7, 0), WDIM - 1);
                const int gkx0 = min(max(x0 - 7 + c, 0), WDIM - 1);
                const int gkx1 = min(max(x0 - 7 + c + 1, 0), WDIM - 1);
                const short* v0 = (const short*)vs + (qb + (size_t)gky * WDIM + gkx0) * HD + h16;
                const short* v1 = (const short*)vs + (qb + (size_t)gky * WDIM + gkx1) * HD + h16;
                const short8 a0 = *(const short8*)v0, b0 = *(const short8*)v1;
                const short8 a1 = *(const short8*)(v0 + 8), b1 = *(const short8*)(v1 + 8);
                #pragma unroll
                for (int dd = 0; dd < 8; ++dd) dstw[dd * 132 + tid] = pk2(a0[dd], b0[dd]);
                #pragma unroll
                for (int dd = 0; dd < 8; ++dd) dstw[(dd + 8) * 132 + tid] = pk2(a1[dd], b1[dd]);
            }
        }
        __syncthreads();
        floatx4 acc = {0.f, 0.f, 0.f, 0.f};
        for (int u = wave; u < 8; u += 4) {          // u = wave, wave+4
            const short8 Af = *(const short8*)(sP + m * 488 + u * 32 + quad * 8);
            const short8 Bf = *(const short8*)(sB + m * 264 + u * 32 + quad * 8);
            acc = __builtin_amdgcn_mfma_f32_16x16x32_bf16(Af, Bf, acc, 0, 0, 0);
        }
        __syncthreads();
        {   // stage V^T chunk1: kk rows 8..14 (kk 256..479), 112 pair-items
            if (tid < 112) {
                unsigned* dstw = (unsigned*)sB;
                const int kk0 = 256 + 2 * tid;
                const int r = kk0 >> 5, c = kk0 & 31;
                const int gky = min(max(y + r - 7, 0), WDIM - 1);
                const int gkx0 = min(max(x0 - 7 + c, 0), WDIM - 1);
                const int gkx1 = min(max(x0 - 7 + c + 1, 0), WDIM - 1);
                const short* v0 = (const short*)vs + (qb + (size_t)gky * WDIM + gkx0) * HD + h16;
                const short* v1 = (const short*)vs + (qb + (size_t)gky * WDIM + gkx1) * HD + h16;
                const short8 a0 = *(const short8*)v0, b0 = *(const short8*)v1;
                const short8 a1 = *(const short8*)(v0 + 8), b1 = *(const short8*)(v1 + 8);
                #pragma unroll
                for (int dd = 0; dd < 8; ++dd) dstw[dd * 132 + tid] = pk2(a0[dd], b0[dd]);
                #pragma unroll
                for (int dd = 0; dd < 8; ++dd) dstw[(dd + 8) * 132 + tid] = pk2(a1[dd], b1[dd]);
            }
        }
        __syncthreads();
        for (int u = 8 + wave; u < 15; u += 4) {     // u = 8+wave, 12+wave
            const short8 Af = *(const short8*)(sP + m * 488 + u * 32 + quad * 8);
            const short8 Bf = *(const short8*)(sB + m * 264 + (u - 8) * 32 + quad * 8);
            acc = __builtin_amdgcn_mfma_f32_16x16x32_bf16(Af, Bf, acc, 0, 0, 0);
        }
        __syncthreads();
        {   // stage Rv^T rows [d-half][kcol], stride 264 shorts; kcol = r*16+dx7,
            // gap cols (dx7==15) and kcol>=240 zero
            unsigned* dstw = (unsigned*)sB;
            for (int p = tid; p < 132; p += 256) {
                short8 a0 = {0,0,0,0,0,0,0,0}, a1 = a0, b0 = a0, b1 = a0;
                if (p < 120) {
                    const int kcol0 = 2 * p;
                    const int r = kcol0 >> 4, dx = kcol0 & 15;   // dx even <= 14
                    const int w0 = r * 15 + dx;                   // <= 224
                    const short* rp = (const short*)relvT + ((size_t)h * WS2 + w0) * HD + h16;
                    a0 = *(const short8*)rp; a1 = *(const short8*)(rp + 8);
                    if (dx < 14) {   // kcol0+1 in-window; dx==14 -> gap col, stays 0
                        const short* rq = (const short*)relvT + ((size_t)h * WS2 + w0 + 1) * HD + h16;
                        b0 = *(const short8*)rq; b1 = *(const short8*)(rq + 8);
                    }
                }
                #pragma unroll
                for (int dd = 0; dd < 8; ++dd) dstw[dd * 132 + p] = pk2(a0[dd], b0[dd]);
                #pragma unroll
                for (int dd = 0; dd < 8; ++dd) dstw[(dd + 8) * 132 + p] = pk2(a1[dd], b1[dd]);
            }
        }
        __syncthreads();
        for (int u = wave; u < 8; u += 4) {
            const short8 Af = *(const short8*)(sPw + m * 264 + u * 32 + quad * 8);
            const short8 Bf = *(const short8*)(sB + m * 264 + u * 32 + quad * 8);
            acc = __builtin_amdgcn_mfma_f32_16x16x32_bf16(Af, Bf, acc, 0, 0, 0);
        }
        __syncthreads();
        #pragma unroll
        for (int rg = 0; rg < 4; ++rg)
            sOh[wave * 256 + (quad * 4 + rg) * 16 + m] = acc[rg];
        __syncthreads();
        {
            const int qq = tid >> 4, dd = tid & 15;
            const float s = sOh[tid] + sOh[256 + tid] + sOh[512 + tid] + sOh[768 + tid];
            if (qq >= wlo) {
                const size_t i = (size_t)y * WDIM + x0 + qq;
                agg[(i * NB + n) * CDIM + h * HD + h16 + dd] = __float2bfloat16(s);
            }
        }
    }
}

// ---------------- Kernel 4: output projection via MFMA (A-frags reused 8x) ------
__global__ __launch_bounds__(256) void out_mfma(
    const __hip_bfloat16* __restrict__ agg, const short* __restrict__ Wpb,
    const float* __restrict__ bpf, const int* __restrict__ flag,
    void* __restrict__ dout)
{
    const bool f32 = (*flag != 0);
    const int wave = threadIdx.x >> 6, lane = threadIdx.x & 63;
    const int rb0 = blockIdx.x << 4;                 // 200 blocks x 16 rows = 3200
    const int m = lane & 15, qd = lane >> 4;

    const __hip_bfloat16* arow = agg + (size_t)(rb0 + m) * CDIM + qd * 8;
    short8 A[8];
    #pragma unroll
    for (int k = 0; k < 8; ++k)
        A[k] = *(const short8*)(arow + k * 32);

    #pragma unroll
    for (int p = 0; p < 2; ++p) {
        const int o0 = wave * 64 + p * 32;           // pair covers o0..o0+31
        floatx4 acc0 = {0.f, 0.f, 0.f, 0.f}, acc1 = {0.f, 0.f, 0.f, 0.f};
        #pragma unroll
        for (int k = 0; k < 8; ++k) {
            short8 b0 = *(const short8*)(Wpb + (size_t)(o0 + m) * CDIM + k * 32 + qd * 8);
            short8 b1 = *(const short8*)(Wpb + (size_t)(o0 + 16 + m) * CDIM + k * 32 + qd * 8);
            acc0 = __builtin_amdgcn_mfma_f32_16x16x32_bf16(A[k], b0, acc0, 0, 0, 0);
            acc1 = __builtin_amdgcn_mfma_f32_16x16x32_bf16(A[k], b1, acc1, 0, 0, 0);
        }
        const int oa = o0 + (lane & 15), ob = oa + 16;
        const float ba_ = bpf[oa];
        const float bb_ = bpf[ob];
        #pragma unroll
        for (int rg = 0; rg < 4; ++rg) {
            const int rb = rb0 + (lane >> 4) * 4 + rg;
            st_out(dout, (size_t)rb * CDIM + oa, acc0[rg] + ba_, f32);
            st_out(dout, (size_t)rb * CDIM + ob, acc1[rg] + bb_, f32);
        }
    }
}

extern "C" void kernel_launch(void* const* d_in, const int* in_sizes, int n_in,
                              void* d_out, int out_size, void* d_ws, size_t ws_size,
                              hipStream_t stream)
{
    const void* q   = d_in[0];
    const void* k   = d_in[1];
    const void* v   = d_in[2];
    const void* Wq  = d_in[3];
    const void* bq  = d_in[4];
    const void* Wk  = d_in[5];
    const void* bk  = d_in[6];
    const void* Wv  = d_in[7];
    const void* bv  = d_in[8];
    const void* rkw = d_in[9];
    const void* rkb = d_in[10];
    const void* rlv = d_in[11];
    const void* Wp  = d_in[12];
    const void* bp  = d_in[13];

    // ws layout (7.32 MB):
    //   flag(64B) | relvT(115200B) | qs | ks | vs | agg (PROJ bf16 each)
    //   | Wqb|Wkb|Wvb|Wpb (131072B each) | rkwb(115200B) | rkbb(3600B)
    //   | bqf|bkf|bvf|bpf (1024B each, fp32)
    char* wsb = (char*)d_ws;
    int* flag = (int*)wsb;
    __hip_bfloat16* relvT = (__hip_bfloat16*)(wsb + 64);
    __hip_bfloat16* qs    = (__hip_bfloat16*)(wsb + 64 + 115200);
    __hip_bfloat16* ks    = qs + PROJ;
    __hip_bfloat16* vs    = ks + PROJ;
    __hip_bfloat16* agg   = vs + PROJ;
    __hip_bfloat16* Wqb   = (__hip_bfloat16*)(wsb + 6668864);
    __hip_bfloat16* Wkb   = Wqb + CDIM * CDIM;
    __hip_bfloat16* Wvb   = Wkb + CDIM * CDIM;
    __hip_bfloat16* Wpb   = Wvb + CDIM * CDIM;
    __hip_bfloat16* rkwb  = (__hip_bfloat16*)(wsb + 7193152);
    __hip_bfloat16* rkbb  = (__hip_bfloat16*)(wsb + 7308352);
    float* bqf = (float*)(wsb + 7311952);
    float* bkf = bqf + CDIM;
    float* bvf = bkf + CDIM;
    float* bpf = bvf + CDIM;

    prep_kernel<<<128, 256, 0, stream>>>(q, rlv, Wq, Wk, Wv, Wp, bq, bk, bv, bp,
                                         rkw, rkb, flag, relvT,
                                         Wqb, Wkb, Wvb, Wpb, bqf, bkf, bvf, bpf,
                                         rkwb, rkbb);
    proj_fused<<<dim3(50, 2, 3), 512, 0, stream>>>(q, k, v, Wqb, bqf, Wkb, bkf,
                                                   Wvb, bvf, flag, qs, ks, vs);
    attn_mfma<<<dim3(120, 16), 256, 0, stream>>>(qs, ks, vs, (const short*)rkwb,
                                                 (const short*)rkbb, relvT, flag,
                                                 agg, d_out);
    out_mfma<<<200, 256, 0, stream>>>(agg, (const short*)Wpb, bpf, flag, d_out);
}